// Round 3
// baseline (934.649 us; speedup 1.0000x reference)
//
#include <hip/hip_runtime.h>
#include <hip/hip_bf16.h>

// ---------------- CSR build ----------------
__global__ __launch_bounds__(256) void k_degree(const int* __restrict__ dst,
                                                int* __restrict__ deg, int e) {
  int i = blockIdx.x * blockDim.x + threadIdx.x;
  if (i < e) atomicAdd(&deg[dst[i]], 1);
}

__global__ __launch_bounds__(256) void k_scan1(const int* __restrict__ deg,
                                               int* __restrict__ rs,
                                               int* __restrict__ bsum, int n) {
  __shared__ int s[256];
  int t = threadIdx.x;
  int i = blockIdx.x * 256 + t;
  int v = (i < n) ? deg[i] : 0;
  s[t] = v;
  __syncthreads();
  for (int off = 1; off < 256; off <<= 1) {
    int u = (t >= off) ? s[t - off] : 0;
    __syncthreads();
    s[t] += u;
    __syncthreads();
  }
  if (i < n) rs[i] = s[t] - v;  // exclusive within block
  if (t == 255) bsum[blockIdx.x] = s[255];
}

__global__ __launch_bounds__(512) void k_scan2(const int* __restrict__ bsum,
                                               int* __restrict__ boff, int nb) {
  __shared__ int s[512];
  int t = threadIdx.x;
  int v = (t < nb) ? bsum[t] : 0;
  s[t] = v;
  __syncthreads();
  for (int off = 1; off < 512; off <<= 1) {
    int u = (t >= off) ? s[t - off] : 0;
    __syncthreads();
    s[t] += u;
    __syncthreads();
  }
  if (t < nb) boff[t] = s[t] - v;  // exclusive
}

__global__ __launch_bounds__(256) void k_scan3(int* __restrict__ rs,
                                               int* __restrict__ cur,
                                               const int* __restrict__ boff,
                                               int n, int e) {
  int i = blockIdx.x * blockDim.x + threadIdx.x;
  if (i < n) {
    int v = rs[i] + boff[i >> 8];
    rs[i] = v;
    cur[i] = v;
  }
  if (i == 0) rs[n] = e;
}

__global__ __launch_bounds__(256) void k_fill(const int* __restrict__ src,
                                              const int* __restrict__ dst,
                                              int* __restrict__ cur,
                                              int* __restrict__ csr, int e) {
  int i = blockIdx.x * blockDim.x + threadIdx.x;
  if (i < e) {
    int p = atomicAdd(&cur[dst[i]], 1);
    csr[p] = src[i];
  }
}

// ---------------- fused dual GEMM: T = X@Wl ; H = X@Wr + b ----------------
// BN = 2*DOUT (256 for dout=128, 128 for dout=64). DIN fixed at 128.
template <int BN>
__global__ __launch_bounds__(256) void k_dual_gemm(
    const float* __restrict__ X, const float* __restrict__ Wl,
    const float* __restrict__ Wr, const float* __restrict__ bias,
    float* __restrict__ T, float* __restrict__ H, int n) {
  constexpr int DIN = 128;
  constexpr int DOUT = BN / 2;
  constexpr int BM = 64;
  constexpr int KT = 16;
  constexpr int NJ = BN / 64;     // 4-col chunks per thread
  constexpr int XPAD = 132;       // 528B row stride: 16B-aligned, conflict-benign
  __shared__ float XS[BM][XPAD];  // 33792 B
  __shared__ float WS[KT][BN];    // 16 KB (BN=256) / 8 KB (BN=128)

  int t = threadIdx.x;
  int br = blockIdx.x * BM;

  // stage X tile (coalesced float4 loads, b128 LDS writes)
  {
    int kq = t & 31;      // k0 = 4*kq
    int rb = t >> 5;      // 0..7
#pragma unroll
    for (int i = 0; i < 8; ++i) {
      int r = rb + i * 8;
      int gr = br + r;
      float4 v = make_float4(0.f, 0.f, 0.f, 0.f);
      if (gr < n) v = *reinterpret_cast<const float4*>(X + (size_t)gr * DIN + kq * 4);
      *reinterpret_cast<float4*>(&XS[r][kq * 4]) = v;
    }
  }

  float4 acc[4][NJ];
#pragma unroll
  for (int rr = 0; rr < 4; ++rr)
#pragma unroll
    for (int j = 0; j < NJ; ++j) acc[rr][j] = make_float4(0.f, 0.f, 0.f, 0.f);

  int rowg = t >> 4, colg = t & 15;
  int r0 = rowg * 4, c0 = colg * 4;

  for (int kc = 0; kc < DIN / KT; ++kc) {
    __syncthreads();
    {  // stage W chunk
      constexpr int C4 = BN / 4;        // float4 columns
      constexpr int RSTEP = 256 / C4;   // rows covered per pass
      int c4 = t % C4;
      int rb = t / C4;
#pragma unroll
      for (int kk = rb; kk < KT; kk += RSTEP) {
        int col = c4 * 4;
        int krow = kc * KT + kk;
        float4 w;
        if (col < DOUT)
          w = *reinterpret_cast<const float4*>(Wl + (size_t)krow * DOUT + col);
        else
          w = *reinterpret_cast<const float4*>(Wr + (size_t)krow * DOUT + (col - DOUT));
        *reinterpret_cast<float4*>(&WS[kk][col]) = w;
      }
    }
    __syncthreads();
#pragma unroll
    for (int kk = 0; kk < KT; ++kk) {
      int k = kc * KT + kk;
      float xv[4];
#pragma unroll
      for (int rr = 0; rr < 4; ++rr) xv[rr] = XS[r0 + rr][k];
#pragma unroll
      for (int j = 0; j < NJ; ++j) {
        float4 w = *reinterpret_cast<const float4*>(&WS[kk][c0 + j * 64]);
#pragma unroll
        for (int rr = 0; rr < 4; ++rr) {
          acc[rr][j].x += xv[rr] * w.x;
          acc[rr][j].y += xv[rr] * w.y;
          acc[rr][j].z += xv[rr] * w.z;
          acc[rr][j].w += xv[rr] * w.w;
        }
      }
    }
  }

  // epilogue: chunks j < NJ/2 -> T, rest -> H (+bias)
#pragma unroll
  for (int rr = 0; rr < 4; ++rr) {
    int gr = br + r0 + rr;
    if (gr >= n) continue;
#pragma unroll
    for (int j = 0; j < NJ; ++j) {
      int col = c0 + j * 64;
      if (col < DOUT) {
        *reinterpret_cast<float4*>(T + (size_t)gr * DOUT + col) = acc[rr][j];
      } else {
        int c = col - DOUT;
        float4 bb = *reinterpret_cast<const float4*>(bias + c);
        float4 v = acc[rr][j];
        v.x += bb.x; v.y += bb.y; v.z += bb.z; v.w += bb.w;
        *reinterpret_cast<float4*>(H + (size_t)gr * DOUT + c) = v;
      }
    }
  }
}

// ---------------- pull-mode mean aggregation: H += mean(T[src]) ----------------
template <int DOUT>
__global__ __launch_bounds__(256) void k_aggregate(const int* __restrict__ rs,
                                                   const int* __restrict__ csr,
                                                   const float* __restrict__ T,
                                                   float* __restrict__ H, int n) {
  int g = (blockIdx.x * blockDim.x + threadIdx.x) >> 5;  // node per 32-lane group
  int lane = threadIdx.x & 31;
  if (g >= n) return;
  int e0 = rs[g], e1 = rs[g + 1];
  float inv = 1.0f / (float)((e1 - e0) > 1 ? (e1 - e0) : 1);
  if constexpr (DOUT == 128) {
    float4 a = make_float4(0.f, 0.f, 0.f, 0.f);
    for (int e = e0; e < e1; ++e) {
      int s = csr[e];
      float4 v = *reinterpret_cast<const float4*>(T + (size_t)s * 128 + lane * 4);
      a.x += v.x; a.y += v.y; a.z += v.z; a.w += v.w;
    }
    float4* hp = reinterpret_cast<float4*>(H + (size_t)g * 128 + lane * 4);
    float4 h = *hp;
    h.x += a.x * inv; h.y += a.y * inv; h.z += a.z * inv; h.w += a.w * inv;
    *hp = h;
  } else {
    float2 a = make_float2(0.f, 0.f);
    for (int e = e0; e < e1; ++e) {
      int s = csr[e];
      float2 v = *reinterpret_cast<const float2*>(T + (size_t)s * 64 + lane * 2);
      a.x += v.x; a.y += v.y;
    }
    float2* hp = reinterpret_cast<float2*>(H + (size_t)g * 64 + lane * 2);
    float2 h = *hp;
    h.x += a.x * inv; h.y += a.y * inv;
    *hp = h;
  }
}

// ---------------- BatchNorm ----------------
template <int DOUT>
__global__ __launch_bounds__(256) void k_bn_stats(const float* __restrict__ H,
                                                  float* __restrict__ sums, int n) {
  constexpr int RPB = 256 / DOUT;
  int f = threadIdx.x % DOUT;
  int rr = threadIdx.x / DOUT;
  float s = 0.f, q = 0.f;
  for (int r = blockIdx.x * RPB + rr; r < n; r += gridDim.x * RPB) {
    float v = H[(size_t)r * DOUT + f];
    s += v;
    q += v * v;
  }
  __shared__ float ls[2][256];
  ls[0][threadIdx.x] = s;
  ls[1][threadIdx.x] = q;
  __syncthreads();
  if (rr == 0) {
#pragma unroll
    for (int i = 1; i < RPB; ++i) {
      s += ls[0][i * DOUT + f];
      q += ls[1][i * DOUT + f];
    }
    atomicAdd(&sums[f], s);
    atomicAdd(&sums[DOUT + f], q);
  }
}

template <int DOUT, bool RELU>
__global__ __launch_bounds__(256) void k_bn_norm(const float* __restrict__ H,
                                                 const float* __restrict__ sums,
                                                 const float* __restrict__ gamma,
                                                 const float* __restrict__ beta,
                                                 float* __restrict__ O, int n) {
  float invn = 1.0f / (float)n;
  int total4 = n * (DOUT / 4);
  for (int idx = blockIdx.x * blockDim.x + threadIdx.x; idx < total4;
       idx += gridDim.x * blockDim.x) {
    int f0 = (idx % (DOUT / 4)) * 4;
    float4 h = reinterpret_cast<const float4*>(H)[idx];
    float hv[4] = {h.x, h.y, h.z, h.w};
    float o[4];
#pragma unroll
    for (int c = 0; c < 4; ++c) {
      int f = f0 + c;
      float m = sums[f] * invn;
      float var = sums[DOUT + f] * invn - m * m;
      float sc = gamma[f] * rsqrtf(var + 1e-5f);
      float sh = beta[f] - m * sc;
      float v = hv[c] * sc + sh;
      if (RELU) v = fmaxf(v, 0.f);
      o[c] = v;
    }
    reinterpret_cast<float4*>(O)[idx] = make_float4(o[0], o[1], o[2], o[3]);
  }
}

// ---------------- host ----------------
extern "C" void kernel_launch(void* const* d_in, const int* in_sizes, int n_in,
                              void* d_out, int out_size, void* d_ws, size_t ws_size,
                              hipStream_t stream) {
  const float* x = (const float*)d_in[0];
  const int* ei = (const int*)d_in[1];
  int n = in_sizes[0] / 128;
  int e = in_sizes[1] / 2;
  const int* src = ei;
  const int* dst = ei + e;

  char* p = (char*)d_ws;
  auto carve = [&](size_t bytes) {
    char* r = p;
    p += (bytes + 255) & ~(size_t)255;
    return r;
  };
  int* deg = (int*)carve((size_t)n * 4);
  int* rs = (int*)carve((size_t)(n + 1) * 4);
  int* cur = (int*)carve((size_t)n * 4);
  int* bsum = (int*)carve(4096);
  int* boff = (int*)carve(4096);
  float* bns = (float*)carve(1024);
  int* csr = (int*)carve((size_t)e * 4);
  float* T = (float*)carve((size_t)n * 128 * 4);
  float* H = (float*)carve((size_t)n * 128 * 4);
  float* Xb = (float*)carve((size_t)n * 128 * 4);

  // ---- CSR (dst-sorted adjacency) ----
  hipMemsetAsync(deg, 0, (size_t)n * 4, stream);
  int gb = (e + 255) / 256;
  int nb1 = (n + 255) / 256;
  k_degree<<<gb, 256, 0, stream>>>(dst, deg, e);
  k_scan1<<<nb1, 256, 0, stream>>>(deg, rs, bsum, n);
  k_scan2<<<1, 512, 0, stream>>>(bsum, boff, nb1);
  k_scan3<<<nb1, 256, 0, stream>>>(rs, cur, boff, n, e);
  k_fill<<<gb, 256, 0, stream>>>(src, dst, cur, csr, e);

  const float* Xcur = x;
  for (int layer = 0; layer < 3; ++layer) {
    const float* Wl = (const float*)d_in[2 + layer * 5];
    const float* Wr = (const float*)d_in[3 + layer * 5];
    const float* bb = (const float*)d_in[4 + layer * 5];
    const float* gm = (const float*)d_in[5 + layer * 5];
    const float* bt = (const float*)d_in[6 + layer * 5];
    int dout = (layer == 2) ? 64 : 128;

    int gg = (n + 63) / 64;
    if (dout == 128)
      k_dual_gemm<256><<<gg, 256, 0, stream>>>(Xcur, Wl, Wr, bb, T, H, n);
    else
      k_dual_gemm<128><<<gg, 256, 0, stream>>>(Xcur, Wl, Wr, bb, T, H, n);

    int ga = (n * 32 + 255) / 256;
    if (dout == 128)
      k_aggregate<128><<<ga, 256, 0, stream>>>(rs, csr, T, H, n);
    else
      k_aggregate<64><<<ga, 256, 0, stream>>>(rs, csr, T, H, n);

    hipMemsetAsync(bns, 0, (size_t)2 * dout * 4, stream);
    if (dout == 128)
      k_bn_stats<128><<<512, 256, 0, stream>>>(H, bns, n);
    else
      k_bn_stats<64><<<512, 256, 0, stream>>>(H, bns, n);

    int total4 = n * dout / 4;
    int gn = (total4 + 255) / 256;
    if (gn > 2048) gn = 2048;
    if (layer == 0)
      k_bn_norm<128, true><<<gn, 256, 0, stream>>>(H, bns, gm, bt, Xb, n);
    else if (layer == 1)
      k_bn_norm<128, true><<<gn, 256, 0, stream>>>(H, bns, gm, bt, Xb, n);
    else
      k_bn_norm<64, false><<<gn, 256, 0, stream>>>(H, bns, gm, bt, (float*)d_out, n);
    Xcur = Xb;
  }
}

// Round 4
// 749.938 us; speedup vs baseline: 1.2463x; 1.2463x over previous
//
#include <hip/hip_runtime.h>
#include <hip/hip_bf16.h>

__device__ __forceinline__ float b2f(unsigned short u) {
  union { unsigned int i; float f; } c;
  c.i = ((unsigned int)u) << 16;
  return c.f;
}
__device__ __forceinline__ unsigned short f2b(float f) {
  union { float f; unsigned int i; } c;
  c.f = f;
  unsigned int x = c.i;
  unsigned int r = x + 0x7fffu + ((x >> 16) & 1u);  // RNE
  return (unsigned short)(r >> 16);
}

// ---------------- CSR build ----------------
__global__ __launch_bounds__(256) void k_degree(const int* __restrict__ dst,
                                                int* __restrict__ deg, int e) {
  int i = blockIdx.x * blockDim.x + threadIdx.x;
  if (i < e) atomicAdd(&deg[dst[i]], 1);
}

__global__ __launch_bounds__(256) void k_scan1(const int* __restrict__ deg,
                                               int* __restrict__ rs,
                                               int* __restrict__ bsum, int n) {
  __shared__ int s[256];
  int t = threadIdx.x;
  int i = blockIdx.x * 256 + t;
  int v = (i < n) ? deg[i] : 0;
  s[t] = v;
  __syncthreads();
  for (int off = 1; off < 256; off <<= 1) {
    int u = (t >= off) ? s[t - off] : 0;
    __syncthreads();
    s[t] += u;
    __syncthreads();
  }
  if (i < n) rs[i] = s[t] - v;
  if (t == 255) bsum[blockIdx.x] = s[255];
}

__global__ __launch_bounds__(512) void k_scan2(const int* __restrict__ bsum,
                                               int* __restrict__ boff, int nb) {
  __shared__ int s[512];
  int t = threadIdx.x;
  int v = (t < nb) ? bsum[t] : 0;
  s[t] = v;
  __syncthreads();
  for (int off = 1; off < 512; off <<= 1) {
    int u = (t >= off) ? s[t - off] : 0;
    __syncthreads();
    s[t] += u;
    __syncthreads();
  }
  if (t < nb) boff[t] = s[t] - v;
}

__global__ __launch_bounds__(256) void k_scan3(int* __restrict__ rs,
                                               int* __restrict__ cur,
                                               const int* __restrict__ boff,
                                               int n, int e) {
  int i = blockIdx.x * blockDim.x + threadIdx.x;
  if (i < n) {
    int v = rs[i] + boff[i >> 8];
    rs[i] = v;
    cur[i] = v;
  }
  if (i == 0) rs[n] = e;
}

__global__ __launch_bounds__(256) void k_fill(const int* __restrict__ src,
                                              const int* __restrict__ dst,
                                              int* __restrict__ cur,
                                              int* __restrict__ csr, int e) {
  int i = blockIdx.x * blockDim.x + threadIdx.x;
  if (i < e) {
    int p = atomicAdd(&cur[dst[i]], 1);
    csr[p] = src[i];
  }
}

// ---------- fused dual GEMM: T16 = bf16(Xeff@Wl) ; H = Xeff@Wr + b ----------
// Xeff = FUSE ? relu(BN(Xraw)) : Xraw, BN params folded at staging time.
// BN template arg = 2*DOUT. DIN fixed at 128.
template <int BNW, bool FUSE>
__global__ __launch_bounds__(256) void k_dual_gemm(
    const float* __restrict__ X, const float* __restrict__ Wl,
    const float* __restrict__ Wr, const float* __restrict__ bias,
    const float* __restrict__ bns, const float* __restrict__ gamma,
    const float* __restrict__ beta, unsigned short* __restrict__ T16,
    float* __restrict__ H, int n) {
  constexpr int DIN = 128;
  constexpr int DOUT = BNW / 2;
  constexpr int BM = 64;
  constexpr int KT = 16;
  constexpr int NJ = BNW / 64;
  constexpr int XPAD = 132;
  __shared__ float XS[BM][XPAD];
  __shared__ float WS[KT][BNW];

  int t = threadIdx.x;
  int br = blockIdx.x * BM;

  // stage X tile; optionally apply BN(scale/shift)+ReLU of the PREVIOUS layer
  {
    int kq = t & 31;  // column quad: features kq*4 .. kq*4+3
    int rb = t >> 5;
    float4 sc4 = make_float4(1.f, 1.f, 1.f, 1.f);
    float4 sh4 = make_float4(0.f, 0.f, 0.f, 0.f);
    if constexpr (FUSE) {
      float invn = 1.0f / (float)n;
      int f0 = kq * 4;
      float4 s1 = *reinterpret_cast<const float4*>(bns + f0);
      float4 s2 = *reinterpret_cast<const float4*>(bns + DIN + f0);
      float4 g4 = *reinterpret_cast<const float4*>(gamma + f0);
      float4 b4 = *reinterpret_cast<const float4*>(beta + f0);
      float m;
      m = s1.x * invn; sc4.x = g4.x * rsqrtf(s2.x * invn - m * m + 1e-5f); sh4.x = b4.x - m * sc4.x;
      m = s1.y * invn; sc4.y = g4.y * rsqrtf(s2.y * invn - m * m + 1e-5f); sh4.y = b4.y - m * sc4.y;
      m = s1.z * invn; sc4.z = g4.z * rsqrtf(s2.z * invn - m * m + 1e-5f); sh4.z = b4.z - m * sc4.z;
      m = s1.w * invn; sc4.w = g4.w * rsqrtf(s2.w * invn - m * m + 1e-5f); sh4.w = b4.w - m * sc4.w;
    }
#pragma unroll
    for (int i = 0; i < 8; ++i) {
      int r = rb + i * 8;
      int gr = br + r;
      float4 v = make_float4(0.f, 0.f, 0.f, 0.f);
      if (gr < n) v = *reinterpret_cast<const float4*>(X + (size_t)gr * DIN + kq * 4);
      if constexpr (FUSE) {
        v.x = fmaxf(v.x * sc4.x + sh4.x, 0.f);
        v.y = fmaxf(v.y * sc4.y + sh4.y, 0.f);
        v.z = fmaxf(v.z * sc4.z + sh4.z, 0.f);
        v.w = fmaxf(v.w * sc4.w + sh4.w, 0.f);
      }
      *reinterpret_cast<float4*>(&XS[r][kq * 4]) = v;
    }
  }

  float4 acc[4][NJ];
#pragma unroll
  for (int rr = 0; rr < 4; ++rr)
#pragma unroll
    for (int j = 0; j < NJ; ++j) acc[rr][j] = make_float4(0.f, 0.f, 0.f, 0.f);

  int rowg = t >> 4, colg = t & 15;
  int r0 = rowg * 4, c0 = colg * 4;

  for (int kc = 0; kc < DIN / KT; ++kc) {
    __syncthreads();
    {
      constexpr int C4 = BNW / 4;
      constexpr int RSTEP = 256 / C4;
      int c4 = t % C4;
      int rb = t / C4;
#pragma unroll
      for (int kk = rb; kk < KT; kk += RSTEP) {
        int col = c4 * 4;
        int krow = kc * KT + kk;
        float4 w;
        if (col < DOUT)
          w = *reinterpret_cast<const float4*>(Wl + (size_t)krow * DOUT + col);
        else
          w = *reinterpret_cast<const float4*>(Wr + (size_t)krow * DOUT + (col - DOUT));
        *reinterpret_cast<float4*>(&WS[kk][col]) = w;
      }
    }
    __syncthreads();
#pragma unroll
    for (int kk = 0; kk < KT; ++kk) {
      int k = kc * KT + kk;
      float xv[4];
#pragma unroll
      for (int rr = 0; rr < 4; ++rr) xv[rr] = XS[r0 + rr][k];
#pragma unroll
      for (int j = 0; j < NJ; ++j) {
        float4 w = *reinterpret_cast<const float4*>(&WS[kk][c0 + j * 64]);
#pragma unroll
        for (int rr = 0; rr < 4; ++rr) {
          acc[rr][j].x += xv[rr] * w.x;
          acc[rr][j].y += xv[rr] * w.y;
          acc[rr][j].z += xv[rr] * w.z;
          acc[rr][j].w += xv[rr] * w.w;
        }
      }
    }
  }

#pragma unroll
  for (int rr = 0; rr < 4; ++rr) {
    int gr = br + r0 + rr;
    if (gr >= n) continue;
#pragma unroll
    for (int j = 0; j < NJ; ++j) {
      int col = c0 + j * 64;
      if (col < DOUT) {
        float4 v = acc[rr][j];
        ushort4 u;
        u.x = f2b(v.x); u.y = f2b(v.y); u.z = f2b(v.z); u.w = f2b(v.w);
        *reinterpret_cast<ushort4*>(T16 + (size_t)gr * DOUT + col) = u;
      } else {
        int c = col - DOUT;
        float4 bb = *reinterpret_cast<const float4*>(bias + c);
        float4 v = acc[rr][j];
        v.x += bb.x; v.y += bb.y; v.z += bb.z; v.w += bb.w;
        *reinterpret_cast<float4*>(H + (size_t)gr * DOUT + c) = v;
      }
    }
  }
}

// -------- pull-mode mean aggregation from bf16 T: H += mean(T[src]) --------
__global__ __launch_bounds__(256) void k_aggregate128(const int* __restrict__ rs,
                                                      const int* __restrict__ csr,
                                                      const unsigned short* __restrict__ T,
                                                      float* __restrict__ H, int n) {
  int g = (blockIdx.x * 256 + threadIdx.x) >> 5;
  int lane = threadIdx.x & 31;
  if (g >= n) return;
  int e0 = rs[g], e1 = rs[g + 1];
  int d = e1 - e0;
  float inv = 1.0f / (float)(d > 1 ? d : 1);
  int off = lane * 4;
  float4 a = make_float4(0.f, 0.f, 0.f, 0.f);
  int e = e0;
  for (; e + 4 <= e1; e += 4) {
    int s0 = csr[e], s1 = csr[e + 1], s2 = csr[e + 2], s3 = csr[e + 3];
    ushort4 v0 = *reinterpret_cast<const ushort4*>(T + (size_t)s0 * 128 + off);
    ushort4 v1 = *reinterpret_cast<const ushort4*>(T + (size_t)s1 * 128 + off);
    ushort4 v2 = *reinterpret_cast<const ushort4*>(T + (size_t)s2 * 128 + off);
    ushort4 v3 = *reinterpret_cast<const ushort4*>(T + (size_t)s3 * 128 + off);
    a.x += (b2f(v0.x) + b2f(v1.x)) + (b2f(v2.x) + b2f(v3.x));
    a.y += (b2f(v0.y) + b2f(v1.y)) + (b2f(v2.y) + b2f(v3.y));
    a.z += (b2f(v0.z) + b2f(v1.z)) + (b2f(v2.z) + b2f(v3.z));
    a.w += (b2f(v0.w) + b2f(v1.w)) + (b2f(v2.w) + b2f(v3.w));
  }
  for (; e < e1; ++e) {
    int s = csr[e];
    ushort4 v = *reinterpret_cast<const ushort4*>(T + (size_t)s * 128 + off);
    a.x += b2f(v.x); a.y += b2f(v.y); a.z += b2f(v.z); a.w += b2f(v.w);
  }
  float4* hp = reinterpret_cast<float4*>(H + (size_t)g * 128 + off);
  float4 h = *hp;
  h.x += a.x * inv; h.y += a.y * inv; h.z += a.z * inv; h.w += a.w * inv;
  *hp = h;
}

__global__ __launch_bounds__(256) void k_aggregate64(const int* __restrict__ rs,
                                                     const int* __restrict__ csr,
                                                     const unsigned short* __restrict__ T,
                                                     float* __restrict__ H, int n) {
  int g = (blockIdx.x * 256 + threadIdx.x) >> 4;
  int lane = threadIdx.x & 15;
  if (g >= n) return;
  int e0 = rs[g], e1 = rs[g + 1];
  int d = e1 - e0;
  float inv = 1.0f / (float)(d > 1 ? d : 1);
  int off = lane * 4;
  float4 a = make_float4(0.f, 0.f, 0.f, 0.f);
  int e = e0;
  for (; e + 4 <= e1; e += 4) {
    int s0 = csr[e], s1 = csr[e + 1], s2 = csr[e + 2], s3 = csr[e + 3];
    ushort4 v0 = *reinterpret_cast<const ushort4*>(T + (size_t)s0 * 64 + off);
    ushort4 v1 = *reinterpret_cast<const ushort4*>(T + (size_t)s1 * 64 + off);
    ushort4 v2 = *reinterpret_cast<const ushort4*>(T + (size_t)s2 * 64 + off);
    ushort4 v3 = *reinterpret_cast<const ushort4*>(T + (size_t)s3 * 64 + off);
    a.x += (b2f(v0.x) + b2f(v1.x)) + (b2f(v2.x) + b2f(v3.x));
    a.y += (b2f(v0.y) + b2f(v1.y)) + (b2f(v2.y) + b2f(v3.y));
    a.z += (b2f(v0.z) + b2f(v1.z)) + (b2f(v2.z) + b2f(v3.z));
    a.w += (b2f(v0.w) + b2f(v1.w)) + (b2f(v2.w) + b2f(v3.w));
  }
  for (; e < e1; ++e) {
    int s = csr[e];
    ushort4 v = *reinterpret_cast<const ushort4*>(T + (size_t)s * 64 + off);
    a.x += b2f(v.x); a.y += b2f(v.y); a.z += b2f(v.z); a.w += b2f(v.w);
  }
  float4* hp = reinterpret_cast<float4*>(H + (size_t)g * 64 + off);
  float4 h = *hp;
  h.x += a.x * inv; h.y += a.y * inv; h.z += a.z * inv; h.w += a.w * inv;
  *hp = h;
}

// ---------------- BatchNorm stats ----------------
template <int DOUT>
__global__ __launch_bounds__(256) void k_bn_stats(const float* __restrict__ H,
                                                  float* __restrict__ sums, int n) {
  constexpr int RPB = 256 / DOUT;
  int f = threadIdx.x % DOUT;
  int rr = threadIdx.x / DOUT;
  float s = 0.f, q = 0.f;
  for (int r = blockIdx.x * RPB + rr; r < n; r += gridDim.x * RPB) {
    float v = H[(size_t)r * DOUT + f];
    s += v;
    q += v * v;
  }
  __shared__ float ls[2][256];
  ls[0][threadIdx.x] = s;
  ls[1][threadIdx.x] = q;
  __syncthreads();
  if (rr == 0) {
#pragma unroll
    for (int i = 1; i < RPB; ++i) {
      s += ls[0][i * DOUT + f];
      q += ls[1][i * DOUT + f];
    }
    atomicAdd(&sums[f], s);
    atomicAdd(&sums[DOUT + f], q);
  }
}

// final norm (layer 2 only) -> d_out
template <int DOUT, bool RELU>
__global__ __launch_bounds__(256) void k_bn_norm(const float* __restrict__ H,
                                                 const float* __restrict__ sums,
                                                 const float* __restrict__ gamma,
                                                 const float* __restrict__ beta,
                                                 float* __restrict__ O, int n) {
  float invn = 1.0f / (float)n;
  int total4 = n * (DOUT / 4);
  for (int idx = blockIdx.x * blockDim.x + threadIdx.x; idx < total4;
       idx += gridDim.x * blockDim.x) {
    int f0 = (idx % (DOUT / 4)) * 4;
    float4 h = reinterpret_cast<const float4*>(H)[idx];
    float hv[4] = {h.x, h.y, h.z, h.w};
    float o[4];
#pragma unroll
    for (int c = 0; c < 4; ++c) {
      int f = f0 + c;
      float m = sums[f] * invn;
      float var = sums[DOUT + f] * invn - m * m;
      float sc = gamma[f] * rsqrtf(var + 1e-5f);
      float sh = beta[f] - m * sc;
      float v = hv[c] * sc + sh;
      if (RELU) v = fmaxf(v, 0.f);
      o[c] = v;
    }
    reinterpret_cast<float4*>(O)[idx] = make_float4(o[0], o[1], o[2], o[3]);
  }
}

// ---------------- host ----------------
extern "C" void kernel_launch(void* const* d_in, const int* in_sizes, int n_in,
                              void* d_out, int out_size, void* d_ws, size_t ws_size,
                              hipStream_t stream) {
  const float* x = (const float*)d_in[0];
  const int* ei = (const int*)d_in[1];
  int n = in_sizes[0] / 128;
  int e = in_sizes[1] / 2;
  const int* src = ei;
  const int* dst = ei + e;

  char* p = (char*)d_ws;
  auto carve = [&](size_t bytes) {
    char* r = p;
    p += (bytes + 255) & ~(size_t)255;
    return r;
  };
  int* deg = (int*)carve((size_t)n * 4);
  int* rs = (int*)carve((size_t)(n + 1) * 4);
  int* cur = (int*)carve((size_t)n * 4);
  int* bsum = (int*)carve(4096);
  int* boff = (int*)carve(4096);
  float* bns = (float*)carve(1024);
  int* csr = (int*)carve((size_t)e * 4);
  unsigned short* T16 = (unsigned short*)carve((size_t)n * 128 * 2);
  float* Ha = (float*)carve((size_t)n * 128 * 4);
  float* Hb = (float*)carve((size_t)n * 128 * 4);

  // ---- CSR (dst-sorted adjacency) ----
  hipMemsetAsync(deg, 0, (size_t)n * 4, stream);
  int gb = (e + 255) / 256;
  int nb1 = (n + 255) / 256;
  k_degree<<<gb, 256, 0, stream>>>(dst, deg, e);
  k_scan1<<<nb1, 256, 0, stream>>>(deg, rs, bsum, n);
  k_scan2<<<1, 512, 0, stream>>>(bsum, boff, nb1);
  k_scan3<<<nb1, 256, 0, stream>>>(rs, cur, boff, n, e);
  k_fill<<<gb, 256, 0, stream>>>(src, dst, cur, csr, e);

  int gg = (n + 63) / 64;
  int ga128 = (n * 32 + 255) / 256;
  int ga64 = (n * 16 + 255) / 256;

  const float* prev_gm = nullptr;
  const float* prev_bt = nullptr;

  for (int layer = 0; layer < 3; ++layer) {
    const float* Wl = (const float*)d_in[2 + layer * 5];
    const float* Wr = (const float*)d_in[3 + layer * 5];
    const float* bb = (const float*)d_in[4 + layer * 5];
    const float* gm = (const float*)d_in[5 + layer * 5];
    const float* bt = (const float*)d_in[6 + layer * 5];

    if (layer == 0) {
      k_dual_gemm<256, false><<<gg, 256, 0, stream>>>(
          x, Wl, Wr, bb, nullptr, nullptr, nullptr, T16, Ha, n);
      k_aggregate128<<<ga128, 256, 0, stream>>>(rs, csr, T16, Ha, n);
      hipMemsetAsync(bns, 0, 256 * 4, stream);
      k_bn_stats<128><<<512, 256, 0, stream>>>(Ha, bns, n);
    } else if (layer == 1) {
      k_dual_gemm<256, true><<<gg, 256, 0, stream>>>(
          Ha, Wl, Wr, bb, bns, prev_gm, prev_bt, T16, Hb, n);
      k_aggregate128<<<ga128, 256, 0, stream>>>(rs, csr, T16, Hb, n);
      hipMemsetAsync(bns, 0, 256 * 4, stream);
      k_bn_stats<128><<<512, 256, 0, stream>>>(Hb, bns, n);
    } else {
      k_dual_gemm<128, true><<<gg, 256, 0, stream>>>(
          Hb, Wl, Wr, bb, bns, prev_gm, prev_bt, T16, Ha, n);
      k_aggregate64<<<ga64, 256, 0, stream>>>(rs, csr, T16, Ha, n);
      hipMemsetAsync(bns, 0, 128 * 4, stream);
      k_bn_stats<64><<<512, 256, 0, stream>>>(Ha, bns, n);
      int total4 = n * 64 / 4;
      int gn = (total4 + 255) / 256;
      if (gn > 2048) gn = 2048;
      k_bn_norm<64, false><<<gn, 256, 0, stream>>>(Ha, bns, gm, bt, (float*)d_out, n);
    }
    prev_gm = gm;
    prev_bt = bt;
  }
}

// Round 7
// 634.458 us; speedup vs baseline: 1.4731x; 1.1820x over previous
//
#include <hip/hip_runtime.h>
#include <hip/hip_bf16.h>

using bf16x8 = __attribute__((ext_vector_type(8))) short;
using f32x4  = __attribute__((ext_vector_type(4))) float;

__device__ __forceinline__ float b2f(unsigned short u) {
  union { unsigned int i; float f; } c;
  c.i = ((unsigned int)u) << 16;
  return c.f;
}
__device__ __forceinline__ unsigned short f2b(float f) {
  union { float f; unsigned int i; } c;
  c.f = f;
  unsigned int x = c.i;
  unsigned int r = x + 0x7fffu + ((x >> 16) & 1u);  // RNE
  return (unsigned short)(r >> 16);
}

// ---------------- CSR build ----------------
__global__ __launch_bounds__(256) void k_degree(const int* __restrict__ dst,
                                                int* __restrict__ deg, int e) {
  int i = blockIdx.x * blockDim.x + threadIdx.x;
  if (i < e) atomicAdd(&deg[dst[i]], 1);
}

__global__ __launch_bounds__(256) void k_scan1(const int* __restrict__ deg,
                                               int* __restrict__ rs,
                                               int* __restrict__ bsum, int n) {
  __shared__ int s[256];
  int t = threadIdx.x;
  int i = blockIdx.x * 256 + t;
  int v = (i < n) ? deg[i] : 0;
  s[t] = v;
  __syncthreads();
  for (int off = 1; off < 256; off <<= 1) {
    int u = (t >= off) ? s[t - off] : 0;
    __syncthreads();
    s[t] += u;
    __syncthreads();
  }
  if (i < n) rs[i] = s[t] - v;
  if (t == 255) bsum[blockIdx.x] = s[255];
}

__global__ __launch_bounds__(512) void k_scan2(const int* __restrict__ bsum,
                                               int* __restrict__ boff, int nb) {
  __shared__ int s[512];
  int t = threadIdx.x;
  int v = (t < nb) ? bsum[t] : 0;
  s[t] = v;
  __syncthreads();
  for (int off = 1; off < 512; off <<= 1) {
    int u = (t >= off) ? s[t - off] : 0;
    __syncthreads();
    s[t] += u;
    __syncthreads();
  }
  if (t < nb) boff[t] = s[t] - v;
}

__global__ __launch_bounds__(256) void k_scan3(int* __restrict__ rs,
                                               int* __restrict__ cur,
                                               const int* __restrict__ boff,
                                               int n, int e) {
  int i = blockIdx.x * blockDim.x + threadIdx.x;
  if (i < n) {
    int v = rs[i] + boff[i >> 8];
    rs[i] = v;
    cur[i] = v;
  }
  if (i == 0) rs[n] = e;
}

__global__ __launch_bounds__(256) void k_fill(const int* __restrict__ src,
                                              const int* __restrict__ dst,
                                              int* __restrict__ cur,
                                              int* __restrict__ csr, int e) {
  int i = blockIdx.x * blockDim.x + threadIdx.x;
  if (i < e) {
    int p = atomicAdd(&cur[dst[i]], 1);
    csr[p] = src[i];
  }
}

// ---------------- weight transpose+convert: WT[n][k] = bf16(W[k][n]) ----------------
template <int NW>
__global__ __launch_bounds__(256) void k_wt(const float* __restrict__ Wl,
                                            const float* __restrict__ Wr,
                                            unsigned short* __restrict__ WT) {
  constexpr int DOUT = NW / 2;
  int idx = blockIdx.x * 256 + threadIdx.x;  // over NW*128
  if (idx >= NW * 128) return;
  int nn = idx >> 7, k = idx & 127;
  float v = (nn < DOUT) ? Wl[(size_t)k * DOUT + nn]
                        : Wr[(size_t)k * DOUT + (nn - DOUT)];
  WT[idx] = f2b(v);
}

// ---------------- X -> bf16 (layer 0), pad rows zeroed ----------------
__global__ __launch_bounds__(256) void k_x0(const float* __restrict__ x,
                                            unsigned short* __restrict__ Xb,
                                            int n, int npad) {
  int total4 = npad * 32;  // 4 elems per thread, DIN=128
  for (int idx = blockIdx.x * 256 + threadIdx.x; idx < total4;
       idx += gridDim.x * 256) {
    int row = idx >> 5;
    ushort4 u = {0, 0, 0, 0};
    if (row < n) {
      float4 v = reinterpret_cast<const float4*>(x)[idx];
      u.x = f2b(v.x); u.y = f2b(v.y); u.z = f2b(v.z); u.w = f2b(v.w);
    }
    reinterpret_cast<ushort4*>(Xb)[idx] = u;
  }
}

// -------- Xb = bf16(relu(BN(H))) for next layer (DIN=128), pad rows zeroed --------
__global__ __launch_bounds__(256) void k_bnrelu(const float* __restrict__ H,
                                                const float* __restrict__ sums,
                                                const float* __restrict__ gamma,
                                                const float* __restrict__ beta,
                                                unsigned short* __restrict__ Xb,
                                                int n, int npad) {
  float invn = 1.0f / (float)n;
  int total4 = npad * 32;
  for (int idx = blockIdx.x * 256 + threadIdx.x; idx < total4;
       idx += gridDim.x * 256) {
    int row = idx >> 5;
    ushort4 u = {0, 0, 0, 0};
    if (row < n) {
      int f0 = (idx & 31) * 4;
      float4 h = reinterpret_cast<const float4*>(H)[idx];
      float hv[4] = {h.x, h.y, h.z, h.w};
      unsigned short uu[4];
#pragma unroll
      for (int c = 0; c < 4; ++c) {
        int f = f0 + c;
        float m = sums[f] * invn;
        float var = sums[128 + f] * invn - m * m;
        float sc = gamma[f] * rsqrtf(var + 1e-5f);
        float sh = beta[f] - m * sc;
        uu[c] = f2b(fmaxf(hv[c] * sc + sh, 0.f));
      }
      u.x = uu[0]; u.y = uu[1]; u.z = uu[2]; u.w = uu[3];
    }
    reinterpret_cast<ushort4*>(Xb)[idx] = u;
  }
}

// ---------------- MFMA dual GEMM: T16 = bf16(Xb@Wl) ; H = Xb@Wr + b ----------------
// Xb: [npad][128] bf16 (row-major). WT: [NW][128] bf16 (= [Wl|Wr]^T).
// 4 waves/block, 64 rows/block. A-frags direct from global; WT staged in LDS
// with XOR swizzle (row-stride 256B b128 reads are 16-way conflicted unswizzled).
template <int NW>
__global__ __launch_bounds__(256) void k_gemm(
    const unsigned short* __restrict__ Xb, const unsigned short* __restrict__ WT,
    const float* __restrict__ bias, unsigned short* __restrict__ T16,
    float* __restrict__ H, int n) {
  constexpr int DOUT = NW / 2;
  constexpr int NT = NW / 16;                 // 16-col tiles
  constexpr int WS_BYTES = NW * 256;          // bf16 [NW][128]
  constexpr int EPR = NW + 4;                 // epilogue row stride (f32), pad 4
  constexpr int EPI_BYTES = 64 * EPR * 4;
  constexpr int SMEM_BYTES = (WS_BYTES > EPI_BYTES ? WS_BYTES : EPI_BYTES);
  __shared__ __align__(16) char smem[SMEM_BYTES];

  int t = threadIdx.x;
  int w = t >> 6;
  int l = t & 63;
  int lg = l >> 4;   // 0..3
  int ll = l & 15;
  int blk = blockIdx.x;
  int row16 = blk * 64 + w * 16;

  // A fragments (all K=128 for this wave's 16 rows): 4 x bf16x8
  bf16x8 af[4];
  {
    const unsigned short* xrow =
        Xb + (size_t)(row16 + ll) * 128 + lg * 8;
#pragma unroll
    for (int s = 0; s < 4; ++s) {
      uint4 u = *reinterpret_cast<const uint4*>(xrow + s * 32);
      af[s] = __builtin_bit_cast(bf16x8, u);
    }
  }

  // stage WT -> LDS, swizzled: byte = row*256 + (slot16 ^ ((row&7)<<4))
  {
    const uint4* wg = reinterpret_cast<const uint4*>(WT);
    constexpr int C16 = NW * 16;
    for (int c = t; c < C16; c += 256) {
      int row = c >> 4;
      unsigned byte = ((unsigned)c << 4) ^ (((unsigned)row & 7u) << 4);
      *reinterpret_cast<uint4*>(smem + byte) = wg[c];
    }
  }
  __syncthreads();

  f32x4 acc[NT];
#pragma unroll
  for (int i = 0; i < NT; ++i) acc[i] = (f32x4){0.f, 0.f, 0.f, 0.f};

#pragma unroll
  for (int s = 0; s < 4; ++s) {       // k-step outer: 16 independent chains inner
#pragma unroll
    for (int ct = 0; ct < NT; ++ct) {
      int row = ct * 16 + ll;
      unsigned byte =
          (unsigned)row * 256u + (((unsigned)(s * 64 + lg * 16)) ^
                                  (((unsigned)row & 7u) << 4));
      uint4 u = *reinterpret_cast<const uint4*>(smem + byte);
      bf16x8 bf = __builtin_bit_cast(bf16x8, u);
      acc[ct] = __builtin_amdgcn_mfma_f32_16x16x32_bf16(af[s], bf, acc[ct], 0, 0, 0);
    }
  }

  // epilogue: acc -> LDS (f32, padded rows) -> coalesced global stores
  __syncthreads();
  float* epi = reinterpret_cast<float*>(smem);
#pragma unroll
  for (int ct = 0; ct < NT; ++ct) {
    int col = ct * 16 + ll;
#pragma unroll
    for (int r = 0; r < 4; ++r) {
      epi[(w * 16 + lg * 4 + r) * EPR + col] = acc[ct][r];
    }
  }
  __syncthreads();

  constexpr int CPR = NW / 4;    // float4 chunks per row
  constexpr int TCH = DOUT / 4;  // chunks -> T16
#pragma unroll
  for (int i = 0; i < NW / 16; ++i) {
    int c = i * 256 + t;
    int row = c / CPR;
    int ch = c % CPR;
    int gr = blk * 64 + row;
    if (gr >= n) continue;
    float4 v = *reinterpret_cast<const float4*>(epi + row * EPR + ch * 4);
    if (ch < TCH) {
      ushort4 u;
      u.x = f2b(v.x); u.y = f2b(v.y); u.z = f2b(v.z); u.w = f2b(v.w);
      *reinterpret_cast<ushort4*>(T16 + (size_t)gr * DOUT + ch * 4) = u;
    } else {
      int cc = (ch - TCH) * 4;
      float4 bb = *reinterpret_cast<const float4*>(bias + cc);
      v.x += bb.x; v.y += bb.y; v.z += bb.z; v.w += bb.w;
      *reinterpret_cast<float4*>(H + (size_t)gr * DOUT + cc) = v;
    }
  }
}

// -------- pull-mode mean aggregation from bf16 T: H += mean(T[src]) --------
__global__ __launch_bounds__(256) void k_aggregate128(const int* __restrict__ rs,
                                                      const int* __restrict__ csr,
                                                      const unsigned short* __restrict__ T,
                                                      float* __restrict__ H, int n) {
  int g = (blockIdx.x * 256 + threadIdx.x) >> 5;
  int lane = threadIdx.x & 31;
  if (g >= n) return;
  int e0 = rs[g], e1 = rs[g + 1];
  int d = e1 - e0;
  float inv = 1.0f / (float)(d > 1 ? d : 1);
  int off = lane * 4;
  float4 a = make_float4(0.f, 0.f, 0.f, 0.f);
  int e = e0;
  for (; e + 4 <= e1; e += 4) {
    int s0 = csr[e], s1 = csr[e + 1], s2 = csr[e + 2], s3 = csr[e + 3];
    ushort4 v0 = *reinterpret_cast<const ushort4*>(T + (size_t)s0 * 128 + off);
    ushort4 v1 = *reinterpret_cast<const ushort4*>(T + (size_t)s1 * 128 + off);
    ushort4 v2 = *reinterpret_cast<const ushort4*>(T + (size_t)s2 * 128 + off);
    ushort4 v3 = *reinterpret_cast<const ushort4*>(T + (size_t)s3 * 128 + off);
    a.x += (b2f(v0.x) + b2f(v1.x)) + (b2f(v2.x) + b2f(v3.x));
    a.y += (b2f(v0.y) + b2f(v1.y)) + (b2f(v2.y) + b2f(v3.y));
    a.z += (b2f(v0.z) + b2f(v1.z)) + (b2f(v2.z) + b2f(v3.z));
    a.w += (b2f(v0.w) + b2f(v1.w)) + (b2f(v2.w) + b2f(v3.w));
  }
  for (; e < e1; ++e) {
    int s = csr[e];
    ushort4 v = *reinterpret_cast<const ushort4*>(T + (size_t)s * 128 + off);
    a.x += b2f(v.x); a.y += b2f(v.y); a.z += b2f(v.z); a.w += b2f(v.w);
  }
  float4* hp = reinterpret_cast<float4*>(H + (size_t)g * 128 + off);
  float4 h = *hp;
  h.x += a.x * inv; h.y += a.y * inv; h.z += a.z * inv; h.w += a.w * inv;
  *hp = h;
}

__global__ __launch_bounds__(256) void k_aggregate64(const int* __restrict__ rs,
                                                     const int* __restrict__ csr,
                                                     const unsigned short* __restrict__ T,
                                                     float* __restrict__ H, int n) {
  int g = (blockIdx.x * 256 + threadIdx.x) >> 4;
  int lane = threadIdx.x & 15;
  if (g >= n) return;
  int e0 = rs[g], e1 = rs[g + 1];
  int d = e1 - e0;
  float inv = 1.0f / (float)(d > 1 ? d : 1);
  int off = lane * 4;
  float4 a = make_float4(0.f, 0.f, 0.f, 0.f);
  int e = e0;
  for (; e + 4 <= e1; e += 4) {
    int s0 = csr[e], s1 = csr[e + 1], s2 = csr[e + 2], s3 = csr[e + 3];
    ushort4 v0 = *reinterpret_cast<const ushort4*>(T + (size_t)s0 * 64 + off);
    ushort4 v1 = *reinterpret_cast<const ushort4*>(T + (size_t)s1 * 64 + off);
    ushort4 v2 = *reinterpret_cast<const ushort4*>(T + (size_t)s2 * 64 + off);
    ushort4 v3 = *reinterpret_cast<const ushort4*>(T + (size_t)s3 * 64 + off);
    a.x += (b2f(v0.x) + b2f(v1.x)) + (b2f(v2.x) + b2f(v3.x));
    a.y += (b2f(v0.y) + b2f(v1.y)) + (b2f(v2.y) + b2f(v3.y));
    a.z += (b2f(v0.z) + b2f(v1.z)) + (b2f(v2.z) + b2f(v3.z));
    a.w += (b2f(v0.w) + b2f(v1.w)) + (b2f(v2.w) + b2f(v3.w));
  }
  for (; e < e1; ++e) {
    int s = csr[e];
    ushort4 v = *reinterpret_cast<const ushort4*>(T + (size_t)s * 64 + off);
    a.x += b2f(v.x); a.y += b2f(v.y); a.z += b2f(v.z); a.w += b2f(v.w);
  }
  float4* hp = reinterpret_cast<float4*>(H + (size_t)g * 64 + off);
  float4 h = *hp;
  h.x += a.x * inv; h.y += a.y * inv; h.z += a.z * inv; h.w += a.w * inv;
  *hp = h;
}

// ---------------- BatchNorm stats ----------------
template <int DOUT>
__global__ __launch_bounds__(256) void k_bn_stats(const float* __restrict__ H,
                                                  float* __restrict__ sums, int n) {
  constexpr int RPB = 256 / DOUT;
  int f = threadIdx.x % DOUT;
  int rr = threadIdx.x / DOUT;
  float s = 0.f, q = 0.f;
  for (int r = blockIdx.x * RPB + rr; r < n; r += gridDim.x * RPB) {
    float v = H[(size_t)r * DOUT + f];
    s += v;
    q += v * v;
  }
  __shared__ float ls[2][256];
  ls[0][threadIdx.x] = s;
  ls[1][threadIdx.x] = q;
  __syncthreads();
  if (rr == 0) {
#pragma unroll
    for (int i = 1; i < RPB; ++i) {
      s += ls[0][i * DOUT + f];
      q += ls[1][i * DOUT + f];
    }
    atomicAdd(&sums[f], s);
    atomicAdd(&sums[DOUT + f], q);
  }
}

// final norm (layer 2 only) -> d_out (f32)
template <int DOUT, bool RELU>
__global__ __launch_bounds__(256) void k_bn_norm(const float* __restrict__ H,
                                                 const float* __restrict__ sums,
                                                 const float* __restrict__ gamma,
                                                 const float* __restrict__ beta,
                                                 float* __restrict__ O, int n) {
  float invn = 1.0f / (float)n;
  int total4 = n * (DOUT / 4);
  for (int idx = blockIdx.x * blockDim.x + threadIdx.x; idx < total4;
       idx += gridDim.x * blockDim.x) {
    int f0 = (idx % (DOUT / 4)) * 4;
    float4 h = reinterpret_cast<const float4*>(H)[idx];
    float hv[4] = {h.x, h.y, h.z, h.w};
    float o[4];
#pragma unroll
    for (int c = 0; c < 4; ++c) {
      int f = f0 + c;
      float m = sums[f] * invn;
      float var = sums[DOUT + f] * invn - m * m;
      float sc = gamma[f] * rsqrtf(var + 1e-5f);
      float sh = beta[f] - m * sc;
      float v = hv[c] * sc + sh;
      if (RELU) v = fmaxf(v, 0.f);
      o[c] = v;
    }
    reinterpret_cast<float4*>(O)[idx] = make_float4(o[0], o[1], o[2], o[3]);
  }
}

// ---------------- host ----------------
extern "C" void kernel_launch(void* const* d_in, const int* in_sizes, int n_in,
                              void* d_out, int out_size, void* d_ws, size_t ws_size,
                              hipStream_t stream) {
  const float* x = (const float*)d_in[0];
  const int* ei = (const int*)d_in[1];
  int n = in_sizes[0] / 128;
  int e = in_sizes[1] / 2;
  int npad = (n + 63) & ~63;
  const int* src = ei;
  const int* dst = ei + e;

  char* p = (char*)d_ws;
  auto carve = [&](size_t bytes) {
    char* r = p;
    p += (bytes + 255) & ~(size_t)255;
    return r;
  };
  int* deg = (int*)carve((size_t)n * 4);
  int* rs = (int*)carve((size_t)(n + 1) * 4);
  int* cur = (int*)carve((size_t)n * 4);
  int* bsum = (int*)carve(4096);
  int* boff = (int*)carve(4096);
  float* bns = (float*)carve(1024);
  unsigned short* WTb = (unsigned short*)carve((size_t)256 * 128 * 2);
  int* csr = (int*)carve((size_t)e * 4);
  unsigned short* T16 = (unsigned short*)carve((size_t)n * 128 * 2);
  unsigned short* Xb = (unsigned short*)carve((size_t)npad * 128 * 2);
  float* Ha = (float*)carve((size_t)n * 128 * 4);
  float* Hb = (float*)carve((size_t)n * 128 * 4);

  // ---- CSR (dst-sorted adjacency) ----
  hipMemsetAsync(deg, 0, (size_t)n * 4, stream);
  int gb = (e + 255) / 256;
  int nb1 = (n + 255) / 256;
  k_degree<<<gb, 256, 0, stream>>>(dst, deg, e);
  k_scan1<<<nb1, 256, 0, stream>>>(deg, rs, bsum, n);
  k_scan2<<<1, 512, 0, stream>>>(bsum, boff, nb1);
  k_scan3<<<nb1, 256, 0, stream>>>(rs, cur, boff, n, e);
  k_fill<<<gb, 256, 0, stream>>>(src, dst, cur, csr, e);

  int gg = npad / 64;
  int ga128 = (n * 32 + 255) / 256;
  int ga64 = (n * 16 + 255) / 256;
  int gcv = 4096;  // grid for conversion passes (grid-stride)

  k_x0<<<gcv, 256, 0, stream>>>(x, Xb, n, npad);

  const float* prev_gm = nullptr;
  const float* prev_bt = nullptr;

  for (int layer = 0; layer < 3; ++layer) {
    const float* Wl = (const float*)d_in[2 + layer * 5];
    const float* Wr = (const float*)d_in[3 + layer * 5];
    const float* bb = (const float*)d_in[4 + layer * 5];
    const float* gm = (const float*)d_in[5 + layer * 5];
    const float* bt = (const float*)d_in[6 + layer * 5];

    if (layer == 0) {
      k_wt<256><<<128, 256, 0, stream>>>(Wl, Wr, WTb);
      k_gemm<256><<<gg, 256, 0, stream>>>(Xb, WTb, bb, T16, Ha, n);
      k_aggregate128<<<ga128, 256, 0, stream>>>(rs, csr, T16, Ha, n);
      hipMemsetAsync(bns, 0, 256 * 4, stream);
      k_bn_stats<128><<<512, 256, 0, stream>>>(Ha, bns, n);
    } else if (layer == 1) {
      k_bnrelu<<<gcv, 256, 0, stream>>>(Ha, bns, prev_gm, prev_bt, Xb, n, npad);
      k_wt<256><<<128, 256, 0, stream>>>(Wl, Wr, WTb);
      k_gemm<256><<<gg, 256, 0, stream>>>(Xb, WTb, bb, T16, Hb, n);
      k_aggregate128<<<ga128, 256, 0, stream>>>(rs, csr, T16, Hb, n);
      hipMemsetAsync(bns, 0, 256 * 4, stream);
      k_bn_stats<128><<<512, 256, 0, stream>>>(Hb, bns, n);
    } else {
      k_bnrelu<<<gcv, 256, 0, stream>>>(Hb, bns, prev_gm, prev_bt, Xb, n, npad);
      k_wt<128><<<64, 256, 0, stream>>>(Wl, Wr, WTb);
      k_gemm<128><<<gg, 256, 0, stream>>>(Xb, WTb, bb, T16, Ha, n);
      k_aggregate64<<<ga64, 256, 0, stream>>>(rs, csr, T16, Ha, n);
      hipMemsetAsync(bns, 0, 128 * 4, stream);
      k_bn_stats<64><<<512, 256, 0, stream>>>(Ha, bns, n);
      int total4 = n * 64 / 4;
      int gn = (total4 + 255) / 256;
      if (gn > 2048) gn = 2048;
      k_bn_norm<64, false><<<gn, 256, 0, stream>>>(Ha, bns, gm, bt, (float*)d_out, n);
    }
    prev_gm = gm;
    prev_bt = bt;
  }
}

// Round 8
// 533.289 us; speedup vs baseline: 1.7526x; 1.1897x over previous
//
#include <hip/hip_runtime.h>
#include <hip/hip_bf16.h>

using bf16x8 = __attribute__((ext_vector_type(8))) short;
using f32x4  = __attribute__((ext_vector_type(4))) float;

__device__ __forceinline__ float b2f(unsigned short u) {
  union { unsigned int i; float f; } c;
  c.i = ((unsigned int)u) << 16;
  return c.f;
}
__device__ __forceinline__ unsigned short f2b(float f) {
  union { float f; unsigned int i; } c;
  c.f = f;
  unsigned int x = c.i;
  unsigned int r = x + 0x7fffu + ((x >> 16) & 1u);  // RNE
  return (unsigned short)(r >> 16);
}

static constexpr int BCAP = 10240;   // bucket capacity (avg 8163 for e=1.6M, >20 sigma)
static constexpr int NBAGG = 1280;   // aggregate grid

// ---------------- CSR build: bucketed two-phase ----------------
// Phase A: partition edges into dst>>9 buckets; packed entry = src | (dst&511)<<17
__global__ __launch_bounds__(256) void k_part(const int* __restrict__ src,
                                              const int* __restrict__ dst,
                                              int* __restrict__ bcnt,
                                              unsigned int* __restrict__ barr,
                                              int e, int nbuk) {
  __shared__ int hist[256];
  __shared__ int base[256];
  __shared__ int h2[256];
  int t = threadIdx.x;
  hist[t] = 0;
  h2[t] = 0;
  __syncthreads();
  int e0 = blockIdx.x * 2048;
  int ms[8], md[8];
#pragma unroll
  for (int i = 0; i < 8; ++i) {
    int idx = e0 + i * 256 + t;
    if (idx < e) {
      ms[i] = src[idx];
      md[i] = dst[idx];
      atomicAdd(&hist[md[i] >> 9], 1);
    } else {
      md[i] = -1;
    }
  }
  __syncthreads();
  if (t < nbuk && hist[t] > 0) base[t] = atomicAdd(&bcnt[t], hist[t]);
  __syncthreads();
#pragma unroll
  for (int i = 0; i < 8; ++i) {
    if (md[i] >= 0) {
      int b = md[i] >> 9;
      int r = atomicAdd(&h2[b], 1);
      int pos = base[b] + r;
      if (pos < BCAP)
        barr[(size_t)b * BCAP + pos] =
            (unsigned int)ms[i] | ((unsigned int)(md[i] & 511) << 17);
    }
  }
}

// per-bucket degree count (dense writes, no global atomics)
__global__ __launch_bounds__(512) void k_bdeg(const int* __restrict__ bcnt,
                                              const unsigned int* __restrict__ barr,
                                              int* __restrict__ deg, int n) {
  __shared__ int cnt[512];
  int t = threadIdx.x;
  int b = blockIdx.x;
  cnt[t] = 0;
  __syncthreads();
  int c = bcnt[b];
  if (c > BCAP) c = BCAP;
  for (int i = t; i < c; i += 512)
    atomicAdd(&cnt[barr[(size_t)b * BCAP + i] >> 17], 1);
  __syncthreads();
  int node = b * 512 + t;
  if (node < n) deg[node] = cnt[t];
}

__global__ __launch_bounds__(256) void k_scan1(const int* __restrict__ deg,
                                               int* __restrict__ rs,
                                               int* __restrict__ bsum, int n) {
  __shared__ int s[256];
  int t = threadIdx.x;
  int i = blockIdx.x * 256 + t;
  int v = (i < n) ? deg[i] : 0;
  s[t] = v;
  __syncthreads();
  for (int off = 1; off < 256; off <<= 1) {
    int u = (t >= off) ? s[t - off] : 0;
    __syncthreads();
    s[t] += u;
    __syncthreads();
  }
  if (i < n) rs[i] = s[t] - v;
  if (t == 255) bsum[blockIdx.x] = s[255];
}

__global__ __launch_bounds__(512) void k_scan2(const int* __restrict__ bsum,
                                               int* __restrict__ boff, int nb) {
  __shared__ int s[512];
  int t = threadIdx.x;
  int v = (t < nb) ? bsum[t] : 0;
  s[t] = v;
  __syncthreads();
  for (int off = 1; off < 512; off <<= 1) {
    int u = (t >= off) ? s[t - off] : 0;
    __syncthreads();
    s[t] += u;
    __syncthreads();
  }
  if (t < nb) boff[t] = s[t] - v;
}

__global__ __launch_bounds__(256) void k_scan3(int* __restrict__ rs,
                                               const int* __restrict__ boff,
                                               int n, int e) {
  int i = blockIdx.x * blockDim.x + threadIdx.x;
  if (i < n) rs[i] = rs[i] + boff[i >> 8];
  if (i == 0) rs[n] = e;
}

// Phase B: place srcs into csr (dense 32KB region per bucket -> write combining)
__global__ __launch_bounds__(512) void k_place(const int* __restrict__ bcnt,
                                               const unsigned int* __restrict__ barr,
                                               const int* __restrict__ rs,
                                               int* __restrict__ csr, int n) {
  __shared__ int cnt[512];
  __shared__ int basep[512];
  int t = threadIdx.x;
  int b = blockIdx.x;
  int node = b * 512 + t;
  basep[t] = (node < n) ? rs[node] : 0;
  cnt[t] = 0;
  __syncthreads();
  int c = bcnt[b];
  if (c > BCAP) c = BCAP;
  for (int i = t; i < c; i += 512) {
    unsigned int v = barr[(size_t)b * BCAP + i];
    int loc = v >> 17;
    int r = atomicAdd(&cnt[loc], 1);
    csr[basep[loc] + r] = (int)(v & 0x1FFFFu);
  }
}

// ---------------- weight transpose+convert: WT[n][k] = bf16(W[k][n]) ----------------
template <int NW>
__global__ __launch_bounds__(256) void k_wt(const float* __restrict__ Wl,
                                            const float* __restrict__ Wr,
                                            unsigned short* __restrict__ WT) {
  constexpr int DOUT = NW / 2;
  int idx = blockIdx.x * 256 + threadIdx.x;
  if (idx >= NW * 128) return;
  int nn = idx >> 7, k = idx & 127;
  float v = (nn < DOUT) ? Wl[(size_t)k * DOUT + nn]
                        : Wr[(size_t)k * DOUT + (nn - DOUT)];
  WT[idx] = f2b(v);
}

// ---------------- X -> bf16 (layer 0), pad rows zeroed ----------------
__global__ __launch_bounds__(256) void k_x0(const float* __restrict__ x,
                                            unsigned short* __restrict__ Xb,
                                            int n, int npad) {
  int total4 = npad * 32;
  for (int idx = blockIdx.x * 256 + threadIdx.x; idx < total4;
       idx += gridDim.x * 256) {
    int row = idx >> 5;
    ushort4 u = {0, 0, 0, 0};
    if (row < n) {
      float4 v = reinterpret_cast<const float4*>(x)[idx];
      u.x = f2b(v.x); u.y = f2b(v.y); u.z = f2b(v.z); u.w = f2b(v.w);
    }
    reinterpret_cast<ushort4*>(Xb)[idx] = u;
  }
}

// -------- Xb = bf16(relu(BN(H))) for next layer (DIN=128), pad rows zeroed --------
__global__ __launch_bounds__(256) void k_bnrelu(const float* __restrict__ H,
                                                const float* __restrict__ sums,
                                                const float* __restrict__ gamma,
                                                const float* __restrict__ beta,
                                                unsigned short* __restrict__ Xb,
                                                int n, int npad) {
  float invn = 1.0f / (float)n;
  int total4 = npad * 32;
  for (int idx = blockIdx.x * 256 + threadIdx.x; idx < total4;
       idx += gridDim.x * 256) {
    int row = idx >> 5;
    ushort4 u = {0, 0, 0, 0};
    if (row < n) {
      int f0 = (idx & 31) * 4;
      float4 h = reinterpret_cast<const float4*>(H)[idx];
      float hv[4] = {h.x, h.y, h.z, h.w};
      unsigned short uu[4];
#pragma unroll
      for (int c = 0; c < 4; ++c) {
        int f = f0 + c;
        float m = sums[f] * invn;
        float var = sums[128 + f] * invn - m * m;
        float sc = gamma[f] * rsqrtf(var + 1e-5f);
        float sh = beta[f] - m * sc;
        uu[c] = f2b(fmaxf(hv[c] * sc + sh, 0.f));
      }
      u.x = uu[0]; u.y = uu[1]; u.z = uu[2]; u.w = uu[3];
    }
    reinterpret_cast<ushort4*>(Xb)[idx] = u;
  }
}

// ---------------- MFMA dual GEMM: T16 = bf16(Xb@Wl) ; H = Xb@Wr + b ----------------
template <int NW>
__global__ __launch_bounds__(256) void k_gemm(
    const unsigned short* __restrict__ Xb, const unsigned short* __restrict__ WT,
    const float* __restrict__ bias, unsigned short* __restrict__ T16,
    float* __restrict__ H, int n) {
  constexpr int DOUT = NW / 2;
  constexpr int NT = NW / 16;
  constexpr int WS_BYTES = NW * 256;
  constexpr int EPR = NW + 4;
  constexpr int EPI_BYTES = 64 * EPR * 4;
  constexpr int SMEM_BYTES = (WS_BYTES > EPI_BYTES ? WS_BYTES : EPI_BYTES);
  __shared__ __align__(16) char smem[SMEM_BYTES];

  int t = threadIdx.x;
  int w = t >> 6;
  int l = t & 63;
  int lg = l >> 4;
  int ll = l & 15;
  int blk = blockIdx.x;
  int row16 = blk * 64 + w * 16;

  bf16x8 af[4];
  {
    const unsigned short* xrow = Xb + (size_t)(row16 + ll) * 128 + lg * 8;
#pragma unroll
    for (int s = 0; s < 4; ++s) {
      uint4 u = *reinterpret_cast<const uint4*>(xrow + s * 32);
      af[s] = __builtin_bit_cast(bf16x8, u);
    }
  }

  {
    const uint4* wg = reinterpret_cast<const uint4*>(WT);
    constexpr int C16 = NW * 16;
    for (int c = t; c < C16; c += 256) {
      int row = c >> 4;
      unsigned byte = ((unsigned)c << 4) ^ (((unsigned)row & 7u) << 4);
      *reinterpret_cast<uint4*>(smem + byte) = wg[c];
    }
  }
  __syncthreads();

  f32x4 acc[NT];
#pragma unroll
  for (int i = 0; i < NT; ++i) acc[i] = (f32x4){0.f, 0.f, 0.f, 0.f};

#pragma unroll
  for (int s = 0; s < 4; ++s) {
#pragma unroll
    for (int ct = 0; ct < NT; ++ct) {
      int row = ct * 16 + ll;
      unsigned byte =
          (unsigned)row * 256u + (((unsigned)(s * 64 + lg * 16)) ^
                                  (((unsigned)row & 7u) << 4));
      uint4 u = *reinterpret_cast<const uint4*>(smem + byte);
      bf16x8 bf = __builtin_bit_cast(bf16x8, u);
      acc[ct] = __builtin_amdgcn_mfma_f32_16x16x32_bf16(af[s], bf, acc[ct], 0, 0, 0);
    }
  }

  __syncthreads();
  float* epi = reinterpret_cast<float*>(smem);
#pragma unroll
  for (int ct = 0; ct < NT; ++ct) {
    int col = ct * 16 + ll;
#pragma unroll
    for (int r = 0; r < 4; ++r) {
      epi[(w * 16 + lg * 4 + r) * EPR + col] = acc[ct][r];
    }
  }
  __syncthreads();

  constexpr int CPR = NW / 4;
  constexpr int TCH = DOUT / 4;
#pragma unroll
  for (int i = 0; i < NW / 16; ++i) {
    int c = i * 256 + t;
    int row = c / CPR;
    int ch = c % CPR;
    int gr = blk * 64 + row;
    if (gr >= n) continue;
    float4 v = *reinterpret_cast<const float4*>(epi + row * EPR + ch * 4);
    if (ch < TCH) {
      ushort4 u;
      u.x = f2b(v.x); u.y = f2b(v.y); u.z = f2b(v.z); u.w = f2b(v.w);
      *reinterpret_cast<ushort4*>(T16 + (size_t)gr * DOUT + ch * 4) = u;
    } else {
      int cc = (ch - TCH) * 4;
      float4 bb = *reinterpret_cast<const float4*>(bias + cc);
      v.x += bb.x; v.y += bb.y; v.z += bb.z; v.w += bb.w;
      *reinterpret_cast<float4*>(H + (size_t)gr * DOUT + cc) = v;
    }
  }
}

// ---- aggregation (pull-mode, bf16 T) fused with BN-stats partial reduction ----
// grid fixed NBAGG blocks; per-block partial sums -> partials[blk][2*DOUT]
__global__ __launch_bounds__(256) void k_agg128(const int* __restrict__ rs,
                                                const int* __restrict__ csr,
                                                const unsigned short* __restrict__ T,
                                                float* __restrict__ H,
                                                float* __restrict__ partials, int n) {
  int t = threadIdx.x;
  int grp = t >> 5, lane = t & 31;
  int off = lane * 4;
  float4 s4 = make_float4(0.f, 0.f, 0.f, 0.f);
  float4 q4 = make_float4(0.f, 0.f, 0.f, 0.f);
  for (int g = blockIdx.x * 8 + grp; g < n; g += NBAGG * 8) {
    int e0 = rs[g], e1 = rs[g + 1];
    int d = e1 - e0;
    float inv = 1.0f / (float)(d > 1 ? d : 1);
    float4 a = make_float4(0.f, 0.f, 0.f, 0.f);
    int e = e0;
    for (; e + 4 <= e1; e += 4) {
      int s0 = csr[e], s1 = csr[e + 1], s2 = csr[e + 2], s3 = csr[e + 3];
      ushort4 v0 = *reinterpret_cast<const ushort4*>(T + (size_t)s0 * 128 + off);
      ushort4 v1 = *reinterpret_cast<const ushort4*>(T + (size_t)s1 * 128 + off);
      ushort4 v2 = *reinterpret_cast<const ushort4*>(T + (size_t)s2 * 128 + off);
      ushort4 v3 = *reinterpret_cast<const ushort4*>(T + (size_t)s3 * 128 + off);
      a.x += (b2f(v0.x) + b2f(v1.x)) + (b2f(v2.x) + b2f(v3.x));
      a.y += (b2f(v0.y) + b2f(v1.y)) + (b2f(v2.y) + b2f(v3.y));
      a.z += (b2f(v0.z) + b2f(v1.z)) + (b2f(v2.z) + b2f(v3.z));
      a.w += (b2f(v0.w) + b2f(v1.w)) + (b2f(v2.w) + b2f(v3.w));
    }
    for (; e < e1; ++e) {
      int s = csr[e];
      ushort4 v = *reinterpret_cast<const ushort4*>(T + (size_t)s * 128 + off);
      a.x += b2f(v.x); a.y += b2f(v.y); a.z += b2f(v.z); a.w += b2f(v.w);
    }
    float4* hp = reinterpret_cast<float4*>(H + (size_t)g * 128 + off);
    float4 h = *hp;
    h.x += a.x * inv; h.y += a.y * inv; h.z += a.z * inv; h.w += a.w * inv;
    *hp = h;
    s4.x += h.x; s4.y += h.y; s4.z += h.z; s4.w += h.w;
    q4.x += h.x * h.x; q4.y += h.y * h.y; q4.z += h.z * h.z; q4.w += h.w * h.w;
  }
  __shared__ float ls[128];
  __shared__ float lq[128];
  if (t < 128) { ls[t] = 0.f; lq[t] = 0.f; }
  __syncthreads();
  atomicAdd(&ls[off + 0], s4.x); atomicAdd(&ls[off + 1], s4.y);
  atomicAdd(&ls[off + 2], s4.z); atomicAdd(&ls[off + 3], s4.w);
  atomicAdd(&lq[off + 0], q4.x); atomicAdd(&lq[off + 1], q4.y);
  atomicAdd(&lq[off + 2], q4.z); atomicAdd(&lq[off + 3], q4.w);
  __syncthreads();
  partials[(size_t)blockIdx.x * 256 + t] = (t < 128) ? ls[t] : lq[t - 128];
}

__global__ __launch_bounds__(256) void k_agg64(const int* __restrict__ rs,
                                               const int* __restrict__ csr,
                                               const unsigned short* __restrict__ T,
                                               float* __restrict__ H,
                                               float* __restrict__ partials, int n) {
  int t = threadIdx.x;
  int grp = t >> 4, lane = t & 15;
  int off = lane * 4;
  float4 s4 = make_float4(0.f, 0.f, 0.f, 0.f);
  float4 q4 = make_float4(0.f, 0.f, 0.f, 0.f);
  for (int g = blockIdx.x * 16 + grp; g < n; g += NBAGG * 16) {
    int e0 = rs[g], e1 = rs[g + 1];
    int d = e1 - e0;
    float inv = 1.0f / (float)(d > 1 ? d : 1);
    float4 a = make_float4(0.f, 0.f, 0.f, 0.f);
    int e = e0;
    for (; e + 4 <= e1; e += 4) {
      int s0 = csr[e], s1 = csr[e + 1], s2 = csr[e + 2], s3 = csr[e + 3];
      ushort4 v0 = *reinterpret_cast<const ushort4*>(T + (size_t)s0 * 64 + off);
      ushort4 v1 = *reinterpret_cast<const ushort4*>(T + (size_t)s1 * 64 + off);
      ushort4 v2 = *reinterpret_cast<const ushort4*>(T + (size_t)s2 * 64 + off);
      ushort4 v3 = *reinterpret_cast<const ushort4*>(T + (size_t)s3 * 64 + off);
      a.x += (b2f(v0.x) + b2f(v1.x)) + (b2f(v2.x) + b2f(v3.x));
      a.y += (b2f(v0.y) + b2f(v1.y)) + (b2f(v2.y) + b2f(v3.y));
      a.z += (b2f(v0.z) + b2f(v1.z)) + (b2f(v2.z) + b2f(v3.z));
      a.w += (b2f(v0.w) + b2f(v1.w)) + (b2f(v2.w) + b2f(v3.w));
    }
    for (; e < e1; ++e) {
      int s = csr[e];
      ushort4 v = *reinterpret_cast<const ushort4*>(T + (size_t)s * 64 + off);
      a.x += b2f(v.x); a.y += b2f(v.y); a.z += b2f(v.z); a.w += b2f(v.w);
    }
    float4* hp = reinterpret_cast<float4*>(H + (size_t)g * 64 + off);
    float4 h = *hp;
    h.x += a.x * inv; h.y += a.y * inv; h.z += a.z * inv; h.w += a.w * inv;
    *hp = h;
    s4.x += h.x; s4.y += h.y; s4.z += h.z; s4.w += h.w;
    q4.x += h.x * h.x; q4.y += h.y * h.y; q4.z += h.z * h.z; q4.w += h.w * h.w;
  }
  __shared__ float ls[64];
  __shared__ float lq[64];
  if (t < 64) { ls[t] = 0.f; lq[t] = 0.f; }
  __syncthreads();
  atomicAdd(&ls[off + 0], s4.x); atomicAdd(&ls[off + 1], s4.y);
  atomicAdd(&ls[off + 2], s4.z); atomicAdd(&ls[off + 3], s4.w);
  atomicAdd(&lq[off + 0], q4.x); atomicAdd(&lq[off + 1], q4.y);
  atomicAdd(&lq[off + 2], q4.z); atomicAdd(&lq[off + 3], q4.w);
  __syncthreads();
  if (t < 128)
    partials[(size_t)blockIdx.x * 128 + t] = (t < 64) ? ls[t] : lq[t - 64];
}

// reduce partials -> bns[2*DOUT]
template <int DOUT>
__global__ __launch_bounds__(256) void k_red(const float* __restrict__ partials,
                                             float* __restrict__ bns) {
  int t = threadIdx.x;
  if (t >= 2 * DOUT) return;
  float acc = 0.f;
  for (int b = 0; b < NBAGG; ++b) acc += partials[(size_t)b * (2 * DOUT) + t];
  bns[t] = acc;
}

// final norm (layer 2 only) -> d_out (f32)
template <int DOUT, bool RELU>
__global__ __launch_bounds__(256) void k_bn_norm(const float* __restrict__ H,
                                                 const float* __restrict__ sums,
                                                 const float* __restrict__ gamma,
                                                 const float* __restrict__ beta,
                                                 float* __restrict__ O, int n) {
  float invn = 1.0f / (float)n;
  int total4 = n * (DOUT / 4);
  for (int idx = blockIdx.x * blockDim.x + threadIdx.x; idx < total4;
       idx += gridDim.x * blockDim.x) {
    int f0 = (idx % (DOUT / 4)) * 4;
    float4 h = reinterpret_cast<const float4*>(H)[idx];
    float hv[4] = {h.x, h.y, h.z, h.w};
    float o[4];
#pragma unroll
    for (int c = 0; c < 4; ++c) {
      int f = f0 + c;
      float m = sums[f] * invn;
      float var = sums[DOUT + f] * invn - m * m;
      float sc = gamma[f] * rsqrtf(var + 1e-5f);
      float sh = beta[f] - m * sc;
      float v = hv[c] * sc + sh;
      if (RELU) v = fmaxf(v, 0.f);
      o[c] = v;
    }
    reinterpret_cast<float4*>(O)[idx] = make_float4(o[0], o[1], o[2], o[3]);
  }
}

// ---------------- host ----------------
extern "C" void kernel_launch(void* const* d_in, const int* in_sizes, int n_in,
                              void* d_out, int out_size, void* d_ws, size_t ws_size,
                              hipStream_t stream) {
  const float* x = (const float*)d_in[0];
  const int* ei = (const int*)d_in[1];
  int n = in_sizes[0] / 128;
  int e = in_sizes[1] / 2;
  int npad = (n + 63) & ~63;
  int nbuk = (n + 511) >> 9;  // 196 for n=100k (<=256 required)
  const int* src = ei;
  const int* dst = ei + e;

  char* p = (char*)d_ws;
  auto carve = [&](size_t bytes) {
    char* r = p;
    p += (bytes + 255) & ~(size_t)255;
    return r;
  };
  int* deg = (int*)carve((size_t)n * 4);
  int* rs = (int*)carve((size_t)(n + 1) * 4);
  int* bcnt = (int*)carve(1024);
  int* bsum = (int*)carve(4096);
  int* boff = (int*)carve(4096);
  float* bns = (float*)carve(1024);
  unsigned short* WTb = (unsigned short*)carve((size_t)256 * 128 * 2);
  float* partials = (float*)carve((size_t)NBAGG * 256 * 4);
  unsigned int* barr = (unsigned int*)carve((size_t)nbuk * BCAP * 4);
  int* csr = (int*)carve((size_t)e * 4);
  unsigned short* T16 = (unsigned short*)carve((size_t)n * 128 * 2);
  unsigned short* Xb = (unsigned short*)carve((size_t)npad * 128 * 2);
  float* Ha = (float*)carve((size_t)n * 128 * 4);
  float* Hb = (float*)carve((size_t)n * 128 * 4);

  // ---- CSR build (bucketed two-phase) ----
  hipMemsetAsync(bcnt, 0, (size_t)nbuk * 4, stream);
  int gA = (e + 2047) / 2048;
  int nb1 = (n + 255) / 256;
  k_part<<<gA, 256, 0, stream>>>(src, dst, bcnt, barr, e, nbuk);
  k_bdeg<<<nbuk, 512, 0, stream>>>(bcnt, barr, deg, n);
  k_scan1<<<nb1, 256, 0, stream>>>(deg, rs, bsum, n);
  k_scan2<<<1, 512, 0, stream>>>(bsum, boff, nb1);
  k_scan3<<<nb1, 256, 0, stream>>>(rs, boff, n, e);
  k_place<<<nbuk, 512, 0, stream>>>(bcnt, barr, rs, csr, n);

  int gg = npad / 64;
  int gcv = 4096;

  k_x0<<<gcv, 256, 0, stream>>>(x, Xb, n, npad);

  const float* prev_gm = nullptr;
  const float* prev_bt = nullptr;

  for (int layer = 0; layer < 3; ++layer) {
    const float* Wl = (const float*)d_in[2 + layer * 5];
    const float* Wr = (const float*)d_in[3 + layer * 5];
    const float* bb = (const float*)d_in[4 + layer * 5];
    const float* gm = (const float*)d_in[5 + layer * 5];
    const float* bt = (const float*)d_in[6 + layer * 5];

    if (layer == 0) {
      k_wt<256><<<128, 256, 0, stream>>>(Wl, Wr, WTb);
      k_gemm<256><<<gg, 256, 0, stream>>>(Xb, WTb, bb, T16, Ha, n);
      k_agg128<<<NBAGG, 256, 0, stream>>>(rs, csr, T16, Ha, partials, n);
      k_red<128><<<1, 256, 0, stream>>>(partials, bns);
    } else if (layer == 1) {
      k_bnrelu<<<gcv, 256, 0, stream>>>(Ha, bns, prev_gm, prev_bt, Xb, n, npad);
      k_wt<256><<<128, 256, 0, stream>>>(Wl, Wr, WTb);
      k_gemm<256><<<gg, 256, 0, stream>>>(Xb, WTb, bb, T16, Hb, n);
      k_agg128<<<NBAGG, 256, 0, stream>>>(rs, csr, T16, Hb, partials, n);
      k_red<128><<<1, 256, 0, stream>>>(partials, bns);
    } else {
      k_bnrelu<<<gcv, 256, 0, stream>>>(Hb, bns, prev_gm, prev_bt, Xb, n, npad);
      k_wt<128><<<64, 256, 0, stream>>>(Wl, Wr, WTb);
      k_gemm<128><<<gg, 256, 0, stream>>>(Xb, WTb, bb, T16, Ha, n);
      k_agg64<<<NBAGG, 256, 0, stream>>>(rs, csr, T16, Ha, partials, n);
      k_red<64><<<1, 256, 0, stream>>>(partials, bns);
      int total4 = n * 64 / 4;
      int gn = (total4 + 255) / 256;
      if (gn > 2048) gn = 2048;
      k_bn_norm<64, false><<<gn, 256, 0, stream>>>(Ha, bns, gm, bt, (float*)d_out, n);
    }
    prev_gm = gm;
    prev_bt = bt;
  }
}

// Round 12
// 492.103 us; speedup vs baseline: 1.8993x; 1.0837x over previous
//
#include <hip/hip_runtime.h>
#include <hip/hip_bf16.h>

using bf16x8 = __attribute__((ext_vector_type(8))) short;
using f32x4  = __attribute__((ext_vector_type(4))) float;

__device__ __forceinline__ float b2f(unsigned short u) {
  union { unsigned int i; float f; } c;
  c.i = ((unsigned int)u) << 16;
  return c.f;
}
__device__ __forceinline__ unsigned short f2b(float f) {
  union { float f; unsigned int i; } c;
  c.f = f;
  unsigned int x = c.i;
  unsigned int r = x + 0x7fffu + ((x >> 16) & 1u);  // RNE
  return (unsigned short)(r >> 16);
}
__device__ __forceinline__ void decb8(uint4 u, float* f) {
  union { uint4 v; unsigned short q[8]; } c;
  c.v = u;
#pragma unroll
  for (int j = 0; j < 8; ++j) f[j] = b2f(c.q[j]);
}
__device__ __forceinline__ void decb4(uint2 u, float* f) {
  union { uint2 v; unsigned short q[4]; } c;
  c.v = u;
#pragma unroll
  for (int j = 0; j < 4; ++j) f[j] = b2f(c.q[j]);
}

static constexpr int BCAP = 10240;
static constexpr int NBAGG = 2048;

// ---------------- CSR build: bucketed two-phase ----------------
__global__ __launch_bounds__(256) void k_part(const int* __restrict__ src,
                                              const int* __restrict__ dst,
                                              int* __restrict__ bcnt,
                                              unsigned int* __restrict__ barr,
                                              int e, int nbuk) {
  __shared__ int hist[256];
  __shared__ int base[256];
  __shared__ int h2[256];
  int t = threadIdx.x;
  hist[t] = 0;
  h2[t] = 0;
  __syncthreads();
  int e0 = blockIdx.x * 2048;
  int ms[8], md[8];
#pragma unroll
  for (int i = 0; i < 8; ++i) {
    int idx = e0 + i * 256 + t;
    if (idx < e) {
      ms[i] = src[idx];
      md[i] = dst[idx];
      atomicAdd(&hist[md[i] >> 9], 1);
    } else {
      md[i] = -1;
    }
  }
  __syncthreads();
  if (t < nbuk && hist[t] > 0) base[t] = atomicAdd(&bcnt[t], hist[t]);
  __syncthreads();
#pragma unroll
  for (int i = 0; i < 8; ++i) {
    if (md[i] >= 0) {
      int b = md[i] >> 9;
      int r = atomicAdd(&h2[b], 1);
      int pos = base[b] + r;
      if (pos < BCAP)
        barr[(size_t)b * BCAP + pos] =
            (unsigned int)ms[i] | ((unsigned int)(md[i] & 511) << 17);
    }
  }
}

__global__ __launch_bounds__(512) void k_bdeg(const int* __restrict__ bcnt,
                                              const unsigned int* __restrict__ barr,
                                              int* __restrict__ deg, int n) {
  __shared__ int cnt[512];
  int t = threadIdx.x;
  int b = blockIdx.x;
  cnt[t] = 0;
  __syncthreads();
  int c = bcnt[b];
  if (c > BCAP) c = BCAP;
  for (int i = t; i < c; i += 512)
    atomicAdd(&cnt[barr[(size_t)b * BCAP + i] >> 17], 1);
  __syncthreads();
  int node = b * 512 + t;
  if (node < n) deg[node] = cnt[t];
}

__global__ __launch_bounds__(256) void k_scan1(const int* __restrict__ deg,
                                               int* __restrict__ rs,
                                               int* __restrict__ bsum, int n) {
  __shared__ int s[256];
  int t = threadIdx.x;
  int i = blockIdx.x * 256 + t;
  int v = (i < n) ? deg[i] : 0;
  s[t] = v;
  __syncthreads();
  for (int off = 1; off < 256; off <<= 1) {
    int u = (t >= off) ? s[t - off] : 0;
    __syncthreads();
    s[t] += u;
    __syncthreads();
  }
  if (i < n) rs[i] = s[t] - v;
  if (t == 255) bsum[blockIdx.x] = s[255];
}

__global__ __launch_bounds__(512) void k_scan2(const int* __restrict__ bsum,
                                               int* __restrict__ boff, int nb) {
  __shared__ int s[512];
  int t = threadIdx.x;
  int v = (t < nb) ? bsum[t] : 0;
  s[t] = v;
  __syncthreads();
  for (int off = 1; off < 512; off <<= 1) {
    int u = (t >= off) ? s[t - off] : 0;
    __syncthreads();
    s[t] += u;
    __syncthreads();
  }
  if (t < nb) boff[t] = s[t] - v;
}

__global__ __launch_bounds__(256) void k_scan3(int* __restrict__ rs,
                                               const int* __restrict__ boff,
                                               int n, int e) {
  int i = blockIdx.x * blockDim.x + threadIdx.x;
  if (i < n) rs[i] = rs[i] + boff[i >> 8];
  if (i == 0) rs[n] = e;
}

__global__ __launch_bounds__(512) void k_place(const int* __restrict__ bcnt,
                                               const unsigned int* __restrict__ barr,
                                               const int* __restrict__ rs,
                                               int* __restrict__ csr, int n) {
  __shared__ int cnt[512];
  __shared__ int basep[512];
  int t = threadIdx.x;
  int b = blockIdx.x;
  int node = b * 512 + t;
  basep[t] = (node < n) ? rs[node] : 0;
  cnt[t] = 0;
  __syncthreads();
  int c = bcnt[b];
  if (c > BCAP) c = BCAP;
  for (int i = t; i < c; i += 512) {
    unsigned int v = barr[(size_t)b * BCAP + i];
    int loc = v >> 17;
    int r = atomicAdd(&cnt[loc], 1);
    csr[basep[loc] + r] = (int)(v & 0x1FFFFu);
  }
}

// ------------- all-layer weight transpose+convert: WT[n][k] = bf16(W[k][n]) -------------
__global__ __launch_bounds__(256) void k_wt_all(
    const float* __restrict__ Wl0, const float* __restrict__ Wr0,
    const float* __restrict__ Wl1, const float* __restrict__ Wr1,
    const float* __restrict__ Wl2, const float* __restrict__ Wr2,
    unsigned short* __restrict__ WT) {
  int idx = blockIdx.x * 256 + threadIdx.x;  // 0..81919
  if (idx >= 81920) return;
  int layer = idx >> 15;
  int r = idx & 32767;
  const float *Wl, *Wr;
  int DOUT;
  if (layer == 0) { Wl = Wl0; Wr = Wr0; DOUT = 128; }
  else if (layer == 1) { Wl = Wl1; Wr = Wr1; DOUT = 128; }
  else { Wl = Wl2; Wr = Wr2; DOUT = 64; }
  int nn = r >> 7, k = r & 127;
  float v = (nn < DOUT) ? Wl[(size_t)k * DOUT + nn]
                        : Wr[(size_t)k * DOUT + (nn - DOUT)];
  WT[idx] = f2b(v);
}

// --------- MFMA dual GEMM with fused input BN+ReLU: ---------
// Xeff = FUSE ? relu(BN(Xf)) : Xf;  T16 = bf16(Xeff@Wl) ; H = Xeff@Wr + b
template <int NW, bool FUSE>
__global__ __launch_bounds__(256) void k_gemm(
    const float* __restrict__ Xf, const unsigned short* __restrict__ WT,
    const float* __restrict__ bias, const float* __restrict__ bns,
    const float* __restrict__ gamma, const float* __restrict__ beta,
    unsigned short* __restrict__ T16, float* __restrict__ H, int n) {
  constexpr int DOUT = NW / 2;
  constexpr int NT = NW / 16;
  constexpr int WS_BYTES = NW * 256;
  constexpr int EPR = NW + 4;
  constexpr int EPI_BYTES = 64 * EPR * 4;
  constexpr int SMEM_BYTES = (WS_BYTES > EPI_BYTES ? WS_BYTES : EPI_BYTES);
  __shared__ __align__(16) char smem[SMEM_BYTES];
  __shared__ float scsh[256];

  int t = threadIdx.x;
  int w = t >> 6;
  int l = t & 63;
  int lg = l >> 4;
  int ll = l & 15;
  int blk = blockIdx.x;
  int row16 = blk * 64 + w * 16;

  if constexpr (FUSE) {
    if (t < 128) {
      float invn = 1.0f / (float)n;
      float m = bns[t] * invn;
      float var = bns[128 + t] * invn - m * m;
      float sc = gamma[t] * rsqrtf(var + 1e-5f);
      scsh[t] = sc;
      scsh[128 + t] = beta[t] - m * sc;
    }
    __syncthreads();
  }

  int row = row16 + ll;
  bool valid = row < n;
  const float* xrow = Xf + (size_t)row * 128 + lg * 8;
  bf16x8 af[4];
#pragma unroll
  for (int s = 0; s < 4; ++s) {
    float v[8];
    if (valid) {
      float4 a = *reinterpret_cast<const float4*>(xrow + s * 32);
      float4 b = *reinterpret_cast<const float4*>(xrow + s * 32 + 4);
      v[0] = a.x; v[1] = a.y; v[2] = a.z; v[3] = a.w;
      v[4] = b.x; v[5] = b.y; v[6] = b.z; v[7] = b.w;
    } else {
#pragma unroll
      for (int j = 0; j < 8; ++j) v[j] = 0.f;
    }
    if constexpr (FUSE) {
#pragma unroll
      for (int j = 0; j < 8; ++j) {
        int f = lg * 8 + s * 32 + j;
        v[j] = fmaxf(v[j] * scsh[f] + scsh[128 + f], 0.f);
      }
    }
    union { unsigned short q[8]; bf16x8 bv; } pk;
#pragma unroll
    for (int j = 0; j < 8; ++j) pk.q[j] = f2b(v[j]);
    af[s] = pk.bv;
  }

  {  // stage WT -> LDS, XOR-swizzled
    const uint4* wg = reinterpret_cast<const uint4*>(WT);
    constexpr int C16 = NW * 16;
    for (int c = t; c < C16; c += 256) {
      int rw = c >> 4;
      unsigned byte = ((unsigned)c << 4) ^ (((unsigned)rw & 7u) << 4);
      *reinterpret_cast<uint4*>(smem + byte) = wg[c];
    }
  }
  __syncthreads();

  f32x4 acc[NT];
#pragma unroll
  for (int i = 0; i < NT; ++i) acc[i] = (f32x4){0.f, 0.f, 0.f, 0.f};

#pragma unroll
  for (int s = 0; s < 4; ++s) {
#pragma unroll
    for (int ct = 0; ct < NT; ++ct) {
      int rw = ct * 16 + ll;
      unsigned byte =
          (unsigned)rw * 256u + (((unsigned)(s * 64 + lg * 16)) ^
                                 (((unsigned)rw & 7u) << 4));
      uint4 u = *reinterpret_cast<const uint4*>(smem + byte);
      bf16x8 bf = __builtin_bit_cast(bf16x8, u);
      acc[ct] = __builtin_amdgcn_mfma_f32_16x16x32_bf16(af[s], bf, acc[ct], 0, 0, 0);
    }
  }

  __syncthreads();
  float* epi = reinterpret_cast<float*>(smem);
#pragma unroll
  for (int ct = 0; ct < NT; ++ct) {
    int col = ct * 16 + ll;
#pragma unroll
    for (int r = 0; r < 4; ++r) {
      epi[(w * 16 + lg * 4 + r) * EPR + col] = acc[ct][r];
    }
  }
  __syncthreads();

  constexpr int CPR = NW / 4;
  constexpr int TCH = DOUT / 4;
#pragma unroll
  for (int i = 0; i < NW / 16; ++i) {
    int c = i * 256 + t;
    int rw = c / CPR;
    int ch = c % CPR;
    int gr = blk * 64 + rw;
    if (gr >= n) continue;
    float4 v = *reinterpret_cast<const float4*>(epi + rw * EPR + ch * 4);
    if (ch < TCH) {
      ushort4 u;
      u.x = f2b(v.x); u.y = f2b(v.y); u.z = f2b(v.z); u.w = f2b(v.w);
      *reinterpret_cast<ushort4*>(T16 + (size_t)gr * DOUT + ch * 4) = u;
    } else {
      int cc = (ch - TCH) * 4;
      float4 bb = *reinterpret_cast<const float4*>(bias + cc);
      v.x += bb.x; v.y += bb.y; v.z += bb.z; v.w += bb.w;
      *reinterpret_cast<float4*>(H + (size_t)gr * DOUT + cc) = v;
    }
  }
}

// ---- pull-mode mean aggregation from bf16 T, fused BN-stats partials ----
__global__ __launch_bounds__(256) void k_agg128(const int* __restrict__ rs,
                                                const int* __restrict__ csr,
                                                const unsigned short* __restrict__ T,
                                                float* __restrict__ H,
                                                float* __restrict__ partials, int n) {
  int t = threadIdx.x;
  int grp = t >> 4, lane = t & 15;
  int off = lane * 8;
  float s8[8], q8[8];
#pragma unroll
  for (int j = 0; j < 8; ++j) { s8[j] = 0.f; q8[j] = 0.f; }
  for (int g = blockIdx.x * 16 + grp; g < n; g += NBAGG * 16) {
    int e0 = rs[g], e1 = rs[g + 1];
    int d = e1 - e0;
    float inv = 1.0f / (float)(d > 1 ? d : 1);
    float a[8];
#pragma unroll
    for (int j = 0; j < 8; ++j) a[j] = 0.f;
    int e = e0;
    for (; e + 4 <= e1; e += 4) {
      int s0 = csr[e], s1 = csr[e + 1], s2 = csr[e + 2], s3 = csr[e + 3];
      uint4 u0 = *reinterpret_cast<const uint4*>(T + (size_t)s0 * 128 + off);
      uint4 u1 = *reinterpret_cast<const uint4*>(T + (size_t)s1 * 128 + off);
      uint4 u2 = *reinterpret_cast<const uint4*>(T + (size_t)s2 * 128 + off);
      uint4 u3 = *reinterpret_cast<const uint4*>(T + (size_t)s3 * 128 + off);
      float f0[8], f1[8], f2[8], f3[8];
      decb8(u0, f0); decb8(u1, f1); decb8(u2, f2); decb8(u3, f3);
#pragma unroll
      for (int j = 0; j < 8; ++j) a[j] += (f0[j] + f1[j]) + (f2[j] + f3[j]);
    }
    for (; e < e1; ++e) {
      int s = csr[e];
      uint4 u = *reinterpret_cast<const uint4*>(T + (size_t)s * 128 + off);
      float f[8];
      decb8(u, f);
#pragma unroll
      for (int j = 0; j < 8; ++j) a[j] += f[j];
    }
    float4* hp0 = reinterpret_cast<float4*>(H + (size_t)g * 128 + off);
    float4* hp1 = hp0 + 1;
    float4 h0 = *hp0, h1 = *hp1;
    float h[8] = {h0.x, h0.y, h0.z, h0.w, h1.x, h1.y, h1.z, h1.w};
#pragma unroll
    for (int j = 0; j < 8; ++j) {
      h[j] += a[j] * inv;
      s8[j] += h[j];
      q8[j] += h[j] * h[j];
    }
    *hp0 = make_float4(h[0], h[1], h[2], h[3]);
    *hp1 = make_float4(h[4], h[5], h[6], h[7]);
  }
  __shared__ float ls[128];
  __shared__ float lq[128];
  if (t < 128) { ls[t] = 0.f; lq[t] = 0.f; }
  __syncthreads();
#pragma unroll
  for (int j = 0; j < 8; ++j) {
    atomicAdd(&ls[off + j], s8[j]);
    atomicAdd(&lq[off + j], q8[j]);
  }
  __syncthreads();
  partials[(size_t)blockIdx.x * 256 + t] = (t < 128) ? ls[t] : lq[t - 128];
}

__global__ __launch_bounds__(256) void k_agg64(const int* __restrict__ rs,
                                               const int* __restrict__ csr,
                                               const unsigned short* __restrict__ T,
                                               float* __restrict__ H,
                                               float* __restrict__ partials, int n) {
  int t = threadIdx.x;
  int grp = t >> 4, lane = t & 15;
  int off = lane * 4;
  float s4[4], q4[4];
#pragma unroll
  for (int j = 0; j < 4; ++j) { s4[j] = 0.f; q4[j] = 0.f; }
  for (int g = blockIdx.x * 16 + grp; g < n; g += NBAGG * 16) {
    int e0 = rs[g], e1 = rs[g + 1];
    int d = e1 - e0;
    float inv = 1.0f / (float)(d > 1 ? d : 1);
    float a[4];
#pragma unroll
    for (int j = 0; j < 4; ++j) a[j] = 0.f;
    int e = e0;
    for (; e + 4 <= e1; e += 4) {
      int s0 = csr[e], s1 = csr[e + 1], s2 = csr[e + 2], s3 = csr[e + 3];
      uint2 u0 = *reinterpret_cast<const uint2*>(T + (size_t)s0 * 64 + off);
      uint2 u1 = *reinterpret_cast<const uint2*>(T + (size_t)s1 * 64 + off);
      uint2 u2 = *reinterpret_cast<const uint2*>(T + (size_t)s2 * 64 + off);
      uint2 u3 = *reinterpret_cast<const uint2*>(T + (size_t)s3 * 64 + off);
      float f0[4], f1[4], f2[4], f3[4];
      decb4(u0, f0); decb4(u1, f1); decb4(u2, f2); decb4(u3, f3);
#pragma unroll
      for (int j = 0; j < 4; ++j) a[j] += (f0[j] + f1[j]) + (f2[j] + f3[j]);
    }
    for (; e < e1; ++e) {
      int s = csr[e];
      uint2 u = *reinterpret_cast<const uint2*>(T + (size_t)s * 64 + off);
      float f[4];
      decb4(u, f);
#pragma unroll
      for (int j = 0; j < 4; ++j) a[j] += f[j];
    }
    float4* hp = reinterpret_cast<float4*>(H + (size_t)g * 64 + off);
    float4 hv = *hp;
    float h[4] = {hv.x, hv.y, hv.z, hv.w};
#pragma unroll
    for (int j = 0; j < 4; ++j) {
      h[j] += a[j] * inv;
      s4[j] += h[j];
      q4[j] += h[j] * h[j];
    }
    *hp = make_float4(h[0], h[1], h[2], h[3]);
  }
  __shared__ float ls[64];
  __shared__ float lq[64];
  if (t < 64) { ls[t] = 0.f; lq[t] = 0.f; }
  __syncthreads();
#pragma unroll
  for (int j = 0; j < 4; ++j) {
    atomicAdd(&ls[off + j], s4[j]);
    atomicAdd(&lq[off + j], q4[j]);
  }
  __syncthreads();
  if (t < 128)
    partials[(size_t)blockIdx.x * 256 + t] = (t < 64) ? ls[t] : lq[t - 64];
}

// reduce partials (stride 256) -> bns; one wave per feature
__global__ __launch_bounds__(64) void k_red(const float* __restrict__ partials,
                                            float* __restrict__ bns) {
  int f = blockIdx.x;
  int j = threadIdx.x;
  float acc = 0.f;
  for (int b = j; b < NBAGG; b += 64) acc += partials[(size_t)b * 256 + f];
#pragma unroll
  for (int off = 32; off > 0; off >>= 1) acc += __shfl_down(acc, off);
  if (j == 0) bns[f] = acc;
}

// final norm (layer 2 only) -> d_out (f32)
template <int DOUT, bool RELU>
__global__ __launch_bounds__(256) void k_bn_norm(const float* __restrict__ H,
                                                 const float* __restrict__ sums,
                                                 const float* __restrict__ gamma,
                                                 const float* __restrict__ beta,
                                                 float* __restrict__ O, int n) {
  float invn = 1.0f / (float)n;
  int total4 = n * (DOUT / 4);
  for (int idx = blockIdx.x * blockDim.x + threadIdx.x; idx < total4;
       idx += gridDim.x * blockDim.x) {
    int f0 = (idx % (DOUT / 4)) * 4;
    float4 h = reinterpret_cast<const float4*>(H)[idx];
    float hv[4] = {h.x, h.y, h.z, h.w};
    float o[4];
#pragma unroll
    for (int c = 0; c < 4; ++c) {
      int f = f0 + c;
      float m = sums[f] * invn;
      float var = sums[DOUT + f] * invn - m * m;
      float sc = gamma[f] * rsqrtf(var + 1e-5f);
      float sh = beta[f] - m * sc;
      float v = hv[c] * sc + sh;
      if (RELU) v = fmaxf(v, 0.f);
      o[c] = v;
    }
    reinterpret_cast<float4*>(O)[idx] = make_float4(o[0], o[1], o[2], o[3]);
  }
}

// ---------------- host ----------------
extern "C" void kernel_launch(void* const* d_in, const int* in_sizes, int n_in,
                              void* d_out, int out_size, void* d_ws, size_t ws_size,
                              hipStream_t stream) {
  const float* x = (const float*)d_in[0];
  const int* ei = (const int*)d_in[1];
  int n = in_sizes[0] / 128;
  int e = in_sizes[1] / 2;
  int npad = (n + 63) & ~63;
  int nbuk = (n + 511) >> 9;
  const int* src = ei;
  const int* dst = ei + e;

  char* p = (char*)d_ws;
  auto carve = [&](size_t bytes) {
    char* r = p;
    p += (bytes + 255) & ~(size_t)255;
    return r;
  };
  int* deg = (int*)carve((size_t)n * 4);
  int* rs = (int*)carve((size_t)(n + 1) * 4);
  int* bcnt = (int*)carve(1024);
  int* bsum = (int*)carve(4096);
  int* boff = (int*)carve(4096);
  float* bns = (float*)carve(1024);
  unsigned short* WTall = (unsigned short*)carve((size_t)81920 * 2);
  float* partials = (float*)carve((size_t)NBAGG * 256 * 4);
  unsigned int* barr = (unsigned int*)carve((size_t)nbuk * BCAP * 4);
  int* csr = (int*)carve((size_t)e * 4);
  unsigned short* T16 = (unsigned short*)carve((size_t)n * 128 * 2);
  float* Ha = (float*)carve((size_t)n * 128 * 4);
  float* Hb = (float*)carve((size_t)n * 128 * 4);

  const float* Wl0 = (const float*)d_in[2];
  const float* Wr0 = (const float*)d_in[3];
  const float* b0 = (const float*)d_in[4];
  const float* gm0 = (const float*)d_in[5];
  const float* bt0 = (const float*)d_in[6];
  const float* Wl1 = (const float*)d_in[7];
  const float* Wr1 = (const float*)d_in[8];
  const float* b1 = (const float*)d_in[9];
  const float* gm1 = (const float*)d_in[10];
  const float* bt1 = (const float*)d_in[11];
  const float* Wl2 = (const float*)d_in[12];
  const float* Wr2 = (const float*)d_in[13];
  const float* b2 = (const float*)d_in[14];
  const float* gm2 = (const float*)d_in[15];
  const float* bt2 = (const float*)d_in[16];

  // ---- CSR build ----
  hipMemsetAsync(bcnt, 0, 1024, stream);
  int gA = (e + 2047) / 2048;
  int nb1 = (n + 255) / 256;
  k_part<<<gA, 256, 0, stream>>>(src, dst, bcnt, barr, e, nbuk);
  k_bdeg<<<nbuk, 512, 0, stream>>>(bcnt, barr, deg, n);
  k_scan1<<<nb1, 256, 0, stream>>>(deg, rs, bsum, n);
  k_scan2<<<1, 512, 0, stream>>>(bsum, boff, nb1);
  k_scan3<<<nb1, 256, 0, stream>>>(rs, boff, n, e);
  k_place<<<nbuk, 512, 0, stream>>>(bcnt, barr, rs, csr, n);

  k_wt_all<<<320, 256, 0, stream>>>(Wl0, Wr0, Wl1, Wr1, Wl2, Wr2, WTall);

  int gg = npad / 64;

  // layer 0
  k_gemm<256, false><<<gg, 256, 0, stream>>>(x, WTall, b0, bns, gm0, bt0, T16, Ha, n);
  k_agg128<<<NBAGG, 256, 0, stream>>>(rs, csr, T16, Ha, partials, n);
  k_red<<<256, 64, 0, stream>>>(partials, bns);
  // layer 1
  k_gemm<256, true><<<gg, 256, 0, stream>>>(Ha, WTall + 32768, b1, bns, gm0, bt0, T16, Hb, n);
  k_agg128<<<NBAGG, 256, 0, stream>>>(rs, csr, T16, Hb, partials, n);
  k_red<<<256, 64, 0, stream>>>(partials, bns);
  // layer 2
  k_gemm<128, true><<<gg, 256, 0, stream>>>(Hb, WTall + 65536, b2, bns, gm1, bt1, T16, Ha, n);
  k_agg64<<<NBAGG, 256, 0, stream>>>(rs, csr, T16, Ha, partials, n);
  k_red<<<128, 64, 0, stream>>>(partials, bns);
  int total4 = n * 64 / 4;
  int gn = (total4 + 255) / 256;
  if (gn > 2048) gn = 2048;
  k_bn_norm<64, false><<<gn, 256, 0, stream>>>(Ha, bns, gm2, bt2, (float*)d_out, n);
}

// Round 13
// 443.448 us; speedup vs baseline: 2.1077x; 1.1097x over previous
//
#include <hip/hip_runtime.h>
#include <hip/hip_bf16.h>

using bf16x8 = __attribute__((ext_vector_type(8))) short;
using f32x4  = __attribute__((ext_vector_type(4))) float;

__device__ __forceinline__ float b2f(unsigned short u) {
  union { unsigned int i; float f; } c;
  c.i = ((unsigned int)u) << 16;
  return c.f;
}
__device__ __forceinline__ unsigned short f2b(float f) {
  union { float f; unsigned int i; } c;
  c.f = f;
  unsigned int x = c.i;
  unsigned int r = x + 0x7fffu + ((x >> 16) & 1u);  // RNE
  return (unsigned short)(r >> 16);
}

static constexpr int BCAP = 10240;
static constexpr int NBAGG = 1280;

// ---------------- CSR build: bucketed two-phase ----------------
__global__ __launch_bounds__(256) void k_part(const int* __restrict__ src,
                                              const int* __restrict__ dst,
                                              int* __restrict__ bcnt,
                                              unsigned int* __restrict__ barr,
                                              int e, int nbuk) {
  __shared__ int hist[256];
  __shared__ int base[256];
  __shared__ int h2[256];
  int t = threadIdx.x;
  hist[t] = 0;
  h2[t] = 0;
  __syncthreads();
  int e0 = blockIdx.x * 2048;
  int ms[8], md[8];
#pragma unroll
  for (int i = 0; i < 8; ++i) {
    int idx = e0 + i * 256 + t;
    if (idx < e) {
      ms[i] = src[idx];
      md[i] = dst[idx];
      atomicAdd(&hist[md[i] >> 9], 1);
    } else {
      md[i] = -1;
    }
  }
  __syncthreads();
  if (t < nbuk && hist[t] > 0) base[t] = atomicAdd(&bcnt[t], hist[t]);
  __syncthreads();
#pragma unroll
  for (int i = 0; i < 8; ++i) {
    if (md[i] >= 0) {
      int b = md[i] >> 9;
      int r = atomicAdd(&h2[b], 1);
      int pos = base[b] + r;
      if (pos < BCAP)
        barr[(size_t)b * BCAP + pos] =
            (unsigned int)ms[i] | ((unsigned int)(md[i] & 511) << 17);
    }
  }
}

__global__ __launch_bounds__(512) void k_bdeg(const int* __restrict__ bcnt,
                                              const unsigned int* __restrict__ barr,
                                              int* __restrict__ deg, int n) {
  __shared__ int cnt[512];
  int t = threadIdx.x;
  int b = blockIdx.x;
  cnt[t] = 0;
  __syncthreads();
  int c = bcnt[b];
  if (c > BCAP) c = BCAP;
  for (int i = t; i < c; i += 512)
    atomicAdd(&cnt[barr[(size_t)b * BCAP + i] >> 17], 1);
  __syncthreads();
  int node = b * 512 + t;
  if (node < n) deg[node] = cnt[t];
}

__global__ __launch_bounds__(256) void k_scan1(const int* __restrict__ deg,
                                               int* __restrict__ rs,
                                               int* __restrict__ bsum, int n) {
  __shared__ int s[256];
  int t = threadIdx.x;
  int i = blockIdx.x * 256 + t;
  int v = (i < n) ? deg[i] : 0;
  s[t] = v;
  __syncthreads();
  for (int off = 1; off < 256; off <<= 1) {
    int u = (t >= off) ? s[t - off] : 0;
    __syncthreads();
    s[t] += u;
    __syncthreads();
  }
  if (i < n) rs[i] = s[t] - v;
  if (t == 255) bsum[blockIdx.x] = s[255];
}

__global__ __launch_bounds__(512) void k_scan2(const int* __restrict__ bsum,
                                               int* __restrict__ boff, int nb) {
  __shared__ int s[512];
  int t = threadIdx.x;
  int v = (t < nb) ? bsum[t] : 0;
  s[t] = v;
  __syncthreads();
  for (int off = 1; off < 512; off <<= 1) {
    int u = (t >= off) ? s[t - off] : 0;
    __syncthreads();
    s[t] += u;
    __syncthreads();
  }
  if (t < nb) boff[t] = s[t] - v;
}

__global__ __launch_bounds__(256) void k_scan3(int* __restrict__ rs,
                                               const int* __restrict__ boff,
                                               int n, int e) {
  int i = blockIdx.x * blockDim.x + threadIdx.x;
  if (i < n) rs[i] = rs[i] + boff[i >> 8];
  if (i == 0) rs[n] = e;
}

__global__ __launch_bounds__(512) void k_place(const int* __restrict__ bcnt,
                                               const unsigned int* __restrict__ barr,
                                               const int* __restrict__ rs,
                                               int* __restrict__ csr, int n) {
  __shared__ int cnt[512];
  __shared__ int basep[512];
  int t = threadIdx.x;
  int b = blockIdx.x;
  int node = b * 512 + t;
  basep[t] = (node < n) ? rs[node] : 0;
  cnt[t] = 0;
  __syncthreads();
  int c = bcnt[b];
  if (c > BCAP) c = BCAP;
  for (int i = t; i < c; i += 512) {
    unsigned int v = barr[(size_t)b * BCAP + i];
    int loc = v >> 17;
    int r = atomicAdd(&cnt[loc], 1);
    csr[basep[loc] + r] = (int)(v & 0x1FFFFu);
  }
}

// ------------- all-layer weight transpose+convert: WT[n][k] = bf16(W[k][n]) -------------
__global__ __launch_bounds__(256) void k_wt_all(
    const float* __restrict__ Wl0, const float* __restrict__ Wr0,
    const float* __restrict__ Wl1, const float* __restrict__ Wr1,
    const float* __restrict__ Wl2, const float* __restrict__ Wr2,
    unsigned short* __restrict__ WT) {
  int idx = blockIdx.x * 256 + threadIdx.x;  // 0..81919
  if (idx >= 81920) return;
  int layer = idx >> 15;
  int r = idx & 32767;
  const float *Wl, *Wr;
  int DOUT;
  if (layer == 0) { Wl = Wl0; Wr = Wr0; DOUT = 128; }
  else if (layer == 1) { Wl = Wl1; Wr = Wr1; DOUT = 128; }
  else { Wl = Wl2; Wr = Wr2; DOUT = 64; }
  int nn = r >> 7, k = r & 127;
  float v = (nn < DOUT) ? Wl[(size_t)k * DOUT + nn]
                        : Wr[(size_t)k * DOUT + (nn - DOUT)];
  WT[idx] = f2b(v);
}

// --------- MFMA dual GEMM with fused input BN+ReLU: ---------
// Xeff = FUSE ? relu(BN(Xf)) : Xf;  T16 = bf16(Xeff@Wl) ; H = Xeff@Wr + b
template <int NW, bool FUSE>
__global__ __launch_bounds__(256) void k_gemm(
    const float* __restrict__ Xf, const unsigned short* __restrict__ WT,
    const float* __restrict__ bias, const float* __restrict__ bns,
    const float* __restrict__ gamma, const float* __restrict__ beta,
    unsigned short* __restrict__ T16, float* __restrict__ H, int n) {
  constexpr int DOUT = NW / 2;
  constexpr int NT = NW / 16;
  constexpr int WS_BYTES = NW * 256;
  constexpr int EPR = NW + 4;
  constexpr int EPI_BYTES = 64 * EPR * 4;
  constexpr int SMEM_BYTES = (WS_BYTES > EPI_BYTES ? WS_BYTES : EPI_BYTES);
  __shared__ __align__(16) char smem[SMEM_BYTES];
  __shared__ float scsh[256];

  int t = threadIdx.x;
  int w = t >> 6;
  int l = t & 63;
  int lg = l >> 4;
  int ll = l & 15;
  int blk = blockIdx.x;
  int row16 = blk * 64 + w * 16;

  if constexpr (FUSE) {
    if (t < 128) {
      float invn = 1.0f / (float)n;
      float m = bns[t] * invn;
      float var = bns[128 + t] * invn - m * m;
      float sc = gamma[t] * rsqrtf(var + 1e-5f);
      scsh[t] = sc;
      scsh[128 + t] = beta[t] - m * sc;
    }
    __syncthreads();
  }

  int row = row16 + ll;
  bool valid = row < n;
  const float* xrow = Xf + (size_t)row * 128 + lg * 8;
  bf16x8 af[4];
#pragma unroll
  for (int s = 0; s < 4; ++s) {
    float v[8];
    if (valid) {
      float4 a = *reinterpret_cast<const float4*>(xrow + s * 32);
      float4 b = *reinterpret_cast<const float4*>(xrow + s * 32 + 4);
      v[0] = a.x; v[1] = a.y; v[2] = a.z; v[3] = a.w;
      v[4] = b.x; v[5] = b.y; v[6] = b.z; v[7] = b.w;
    } else {
#pragma unroll
      for (int j = 0; j < 8; ++j) v[j] = 0.f;
    }
    if constexpr (FUSE) {
#pragma unroll
      for (int j = 0; j < 8; ++j) {
        int f = lg * 8 + s * 32 + j;
        v[j] = fmaxf(v[j] * scsh[f] + scsh[128 + f], 0.f);
      }
    }
    union { unsigned short q[8]; bf16x8 bv; } pk;
#pragma unroll
    for (int j = 0; j < 8; ++j) pk.q[j] = f2b(v[j]);
    af[s] = pk.bv;
  }

  {  // stage WT -> LDS, XOR-swizzled
    const uint4* wg = reinterpret_cast<const uint4*>(WT);
    constexpr int C16 = NW * 16;
    for (int c = t; c < C16; c += 256) {
      int rw = c >> 4;
      unsigned byte = ((unsigned)c << 4) ^ (((unsigned)rw & 7u) << 4);
      *reinterpret_cast<uint4*>(smem + byte) = wg[c];
    }
  }
  __syncthreads();

  f32x4 acc[NT];
#pragma unroll
  for (int i = 0; i < NT; ++i) acc[i] = (f32x4){0.f, 0.f, 0.f, 0.f};

#pragma unroll
  for (int s = 0; s < 4; ++s) {
#pragma unroll
    for (int ct = 0; ct < NT; ++ct) {
      int rw = ct * 16 + ll;
      unsigned byte =
          (unsigned)rw * 256u + (((unsigned)(s * 64 + lg * 16)) ^
                                 (((unsigned)rw & 7u) << 4));
      uint4 u = *reinterpret_cast<const uint4*>(smem + byte);
      bf16x8 bf = __builtin_bit_cast(bf16x8, u);
      acc[ct] = __builtin_amdgcn_mfma_f32_16x16x32_bf16(af[s], bf, acc[ct], 0, 0, 0);
    }
  }

  __syncthreads();
  float* epi = reinterpret_cast<float*>(smem);
#pragma unroll
  for (int ct = 0; ct < NT; ++ct) {
    int col = ct * 16 + ll;
#pragma unroll
    for (int r = 0; r < 4; ++r) {
      epi[(w * 16 + lg * 4 + r) * EPR + col] = acc[ct][r];
    }
  }
  __syncthreads();

  constexpr int CPR = NW / 4;
  constexpr int TCH = DOUT / 4;
#pragma unroll
  for (int i = 0; i < NW / 16; ++i) {
    int c = i * 256 + t;
    int rw = c / CPR;
    int ch = c % CPR;
    int gr = blk * 64 + rw;
    if (gr >= n) continue;
    float4 v = *reinterpret_cast<const float4*>(epi + rw * EPR + ch * 4);
    if (ch < TCH) {
      ushort4 u;
      u.x = f2b(v.x); u.y = f2b(v.y); u.z = f2b(v.z); u.w = f2b(v.w);
      *reinterpret_cast<ushort4*>(T16 + (size_t)gr * DOUT + ch * 4) = u;
    } else {
      int cc = (ch - TCH) * 4;
      float4 bb = *reinterpret_cast<const float4*>(bias + cc);
      v.x += bb.x; v.y += bb.y; v.z += bb.z; v.w += bb.w;
      *reinterpret_cast<float4*>(H + (size_t)gr * DOUT + cc) = v;
    }
  }
}

// ---- pull-mode mean aggregation (round-8 structure: 32-lane groups, 8B loads) ----
// fused BN-stats partials at stride 256
__global__ __launch_bounds__(256) void k_agg128(const int* __restrict__ rs,
                                                const int* __restrict__ csr,
                                                const unsigned short* __restrict__ T,
                                                float* __restrict__ H,
                                                float* __restrict__ partials, int n) {
  int t = threadIdx.x;
  int grp = t >> 5, lane = t & 31;
  int off = lane * 4;
  float4 s4 = make_float4(0.f, 0.f, 0.f, 0.f);
  float4 q4 = make_float4(0.f, 0.f, 0.f, 0.f);
  for (int g = blockIdx.x * 8 + grp; g < n; g += NBAGG * 8) {
    int e0 = rs[g], e1 = rs[g + 1];
    int d = e1 - e0;
    float inv = 1.0f / (float)(d > 1 ? d : 1);
    float4 a = make_float4(0.f, 0.f, 0.f, 0.f);
    int e = e0;
    for (; e + 4 <= e1; e += 4) {
      int s0 = csr[e], s1 = csr[e + 1], s2 = csr[e + 2], s3 = csr[e + 3];
      ushort4 v0 = *reinterpret_cast<const ushort4*>(T + (size_t)s0 * 128 + off);
      ushort4 v1 = *reinterpret_cast<const ushort4*>(T + (size_t)s1 * 128 + off);
      ushort4 v2 = *reinterpret_cast<const ushort4*>(T + (size_t)s2 * 128 + off);
      ushort4 v3 = *reinterpret_cast<const ushort4*>(T + (size_t)s3 * 128 + off);
      a.x += (b2f(v0.x) + b2f(v1.x)) + (b2f(v2.x) + b2f(v3.x));
      a.y += (b2f(v0.y) + b2f(v1.y)) + (b2f(v2.y) + b2f(v3.y));
      a.z += (b2f(v0.z) + b2f(v1.z)) + (b2f(v2.z) + b2f(v3.z));
      a.w += (b2f(v0.w) + b2f(v1.w)) + (b2f(v2.w) + b2f(v3.w));
    }
    for (; e < e1; ++e) {
      int s = csr[e];
      ushort4 v = *reinterpret_cast<const ushort4*>(T + (size_t)s * 128 + off);
      a.x += b2f(v.x); a.y += b2f(v.y); a.z += b2f(v.z); a.w += b2f(v.w);
    }
    float4* hp = reinterpret_cast<float4*>(H + (size_t)g * 128 + off);
    float4 h = *hp;
    h.x += a.x * inv; h.y += a.y * inv; h.z += a.z * inv; h.w += a.w * inv;
    *hp = h;
    s4.x += h.x; s4.y += h.y; s4.z += h.z; s4.w += h.w;
    q4.x += h.x * h.x; q4.y += h.y * h.y; q4.z += h.z * h.z; q4.w += h.w * h.w;
  }
  __shared__ float ls[128];
  __shared__ float lq[128];
  if (t < 128) { ls[t] = 0.f; lq[t] = 0.f; }
  __syncthreads();
  atomicAdd(&ls[off + 0], s4.x); atomicAdd(&ls[off + 1], s4.y);
  atomicAdd(&ls[off + 2], s4.z); atomicAdd(&ls[off + 3], s4.w);
  atomicAdd(&lq[off + 0], q4.x); atomicAdd(&lq[off + 1], q4.y);
  atomicAdd(&lq[off + 2], q4.z); atomicAdd(&lq[off + 3], q4.w);
  __syncthreads();
  partials[(size_t)blockIdx.x * 256 + t] = (t < 128) ? ls[t] : lq[t - 128];
}

__global__ __launch_bounds__(256) void k_agg64(const int* __restrict__ rs,
                                               const int* __restrict__ csr,
                                               const unsigned short* __restrict__ T,
                                               float* __restrict__ H,
                                               float* __restrict__ partials, int n) {
  int t = threadIdx.x;
  int grp = t >> 4, lane = t & 15;
  int off = lane * 4;
  float4 s4 = make_float4(0.f, 0.f, 0.f, 0.f);
  float4 q4 = make_float4(0.f, 0.f, 0.f, 0.f);
  for (int g = blockIdx.x * 16 + grp; g < n; g += NBAGG * 16) {
    int e0 = rs[g], e1 = rs[g + 1];
    int d = e1 - e0;
    float inv = 1.0f / (float)(d > 1 ? d : 1);
    float4 a = make_float4(0.f, 0.f, 0.f, 0.f);
    int e = e0;
    for (; e + 4 <= e1; e += 4) {
      int s0 = csr[e], s1 = csr[e + 1], s2 = csr[e + 2], s3 = csr[e + 3];
      ushort4 v0 = *reinterpret_cast<const ushort4*>(T + (size_t)s0 * 64 + off);
      ushort4 v1 = *reinterpret_cast<const ushort4*>(T + (size_t)s1 * 64 + off);
      ushort4 v2 = *reinterpret_cast<const ushort4*>(T + (size_t)s2 * 64 + off);
      ushort4 v3 = *reinterpret_cast<const ushort4*>(T + (size_t)s3 * 64 + off);
      a.x += (b2f(v0.x) + b2f(v1.x)) + (b2f(v2.x) + b2f(v3.x));
      a.y += (b2f(v0.y) + b2f(v1.y)) + (b2f(v2.y) + b2f(v3.y));
      a.z += (b2f(v0.z) + b2f(v1.z)) + (b2f(v2.z) + b2f(v3.z));
      a.w += (b2f(v0.w) + b2f(v1.w)) + (b2f(v2.w) + b2f(v3.w));
    }
    for (; e < e1; ++e) {
      int s = csr[e];
      ushort4 v = *reinterpret_cast<const ushort4*>(T + (size_t)s * 64 + off);
      a.x += b2f(v.x); a.y += b2f(v.y); a.z += b2f(v.z); a.w += b2f(v.w);
    }
    float4* hp = reinterpret_cast<float4*>(H + (size_t)g * 64 + off);
    float4 h = *hp;
    h.x += a.x * inv; h.y += a.y * inv; h.z += a.z * inv; h.w += a.w * inv;
    *hp = h;
    s4.x += h.x; s4.y += h.y; s4.z += h.z; s4.w += h.w;
    q4.x += h.x * h.x; q4.y += h.y * h.y; q4.z += h.z * h.z; q4.w += h.w * h.w;
  }
  __shared__ float ls[64];
  __shared__ float lq[64];
  if (t < 64) { ls[t] = 0.f; lq[t] = 0.f; }
  __syncthreads();
  atomicAdd(&ls[off + 0], s4.x); atomicAdd(&ls[off + 1], s4.y);
  atomicAdd(&ls[off + 2], s4.z); atomicAdd(&ls[off + 3], s4.w);
  atomicAdd(&lq[off + 0], q4.x); atomicAdd(&lq[off + 1], q4.y);
  atomicAdd(&lq[off + 2], q4.z); atomicAdd(&lq[off + 3], q4.w);
  __syncthreads();
  if (t < 128)
    partials[(size_t)blockIdx.x * 256 + t] = (t < 64) ? ls[t] : lq[t - 64];
}

// reduce partials (stride 256) -> bns; one wave per feature
__global__ __launch_bounds__(64) void k_red(const float* __restrict__ partials,
                                            float* __restrict__ bns) {
  int f = blockIdx.x;
  int j = threadIdx.x;
  float acc = 0.f;
  for (int b = j; b < NBAGG; b += 64) acc += partials[(size_t)b * 256 + f];
#pragma unroll
  for (int off = 32; off > 0; off >>= 1) acc += __shfl_down(acc, off);
  if (j == 0) bns[f] = acc;
}

// final norm (layer 2 only) -> d_out (f32)
template <int DOUT, bool RELU>
__global__ __launch_bounds__(256) void k_bn_norm(const float* __restrict__ H,
                                                 const float* __restrict__ sums,
                                                 const float* __restrict__ gamma,
                                                 const float* __restrict__ beta,
                                                 float* __restrict__ O, int n) {
  float invn = 1.0f / (float)n;
  int total4 = n * (DOUT / 4);
  for (int idx = blockIdx.x * blockDim.x + threadIdx.x; idx < total4;
       idx += gridDim.x * blockDim.x) {
    int f0 = (idx % (DOUT / 4)) * 4;
    float4 h = reinterpret_cast<const float4*>(H)[idx];
    float hv[4] = {h.x, h.y, h.z, h.w};
    float o[4];
#pragma unroll
    for (int c = 0; c < 4; ++c) {
      int f = f0 + c;
      float m = sums[f] * invn;
      float var = sums[DOUT + f] * invn - m * m;
      float sc = gamma[f] * rsqrtf(var + 1e-5f);
      float sh = beta[f] - m * sc;
      float v = hv[c] * sc + sh;
      if (RELU) v = fmaxf(v, 0.f);
      o[c] = v;
    }
    reinterpret_cast<float4*>(O)[idx] = make_float4(o[0], o[1], o[2], o[3]);
  }
}

// ---------------- host ----------------
extern "C" void kernel_launch(void* const* d_in, const int* in_sizes, int n_in,
                              void* d_out, int out_size, void* d_ws, size_t ws_size,
                              hipStream_t stream) {
  const float* x = (const float*)d_in[0];
  const int* ei = (const int*)d_in[1];
  int n = in_sizes[0] / 128;
  int e = in_sizes[1] / 2;
  int npad = (n + 63) & ~63;
  int nbuk = (n + 511) >> 9;
  const int* src = ei;
  const int* dst = ei + e;

  char* p = (char*)d_ws;
  auto carve = [&](size_t bytes) {
    char* r = p;
    p += (bytes + 255) & ~(size_t)255;
    return r;
  };
  int* deg = (int*)carve((size_t)n * 4);
  int* rs = (int*)carve((size_t)(n + 1) * 4);
  int* bcnt = (int*)carve(1024);
  int* bsum = (int*)carve(4096);
  int* boff = (int*)carve(4096);
  float* bns = (float*)carve(1024);
  unsigned short* WTall = (unsigned short*)carve((size_t)81920 * 2);
  float* partials = (float*)carve((size_t)NBAGG * 256 * 4);
  unsigned int* barr = (unsigned int*)carve((size_t)nbuk * BCAP * 4);
  int* csr = (int*)carve((size_t)e * 4);
  unsigned short* T16 = (unsigned short*)carve((size_t)n * 128 * 2);
  float* Ha = (float*)carve((size_t)n * 128 * 4);
  float* Hb = (float*)carve((size_t)n * 128 * 4);

  const float* Wl0 = (const float*)d_in[2];
  const float* Wr0 = (const float*)d_in[3];
  const float* b0 = (const float*)d_in[4];
  const float* gm0 = (const float*)d_in[5];
  const float* bt0 = (const float*)d_in[6];
  const float* Wl1 = (const float*)d_in[7];
  const float* Wr1 = (const float*)d_in[8];
  const float* b1 = (const float*)d_in[9];
  const float* gm1 = (const float*)d_in[10];
  const float* bt1 = (const float*)d_in[11];
  const float* Wl2 = (const float*)d_in[12];
  const float* Wr2 = (const float*)d_in[13];
  const float* b2 = (const float*)d_in[14];
  const float* gm2 = (const float*)d_in[15];
  const float* bt2 = (const float*)d_in[16];

  // ---- CSR build ----
  hipMemsetAsync(bcnt, 0, 1024, stream);
  int gA = (e + 2047) / 2048;
  int nb1 = (n + 255) / 256;
  k_part<<<gA, 256, 0, stream>>>(src, dst, bcnt, barr, e, nbuk);
  k_bdeg<<<nbuk, 512, 0, stream>>>(bcnt, barr, deg, n);
  k_scan1<<<nb1, 256, 0, stream>>>(deg, rs, bsum, n);
  k_scan2<<<1, 512, 0, stream>>>(bsum, boff, nb1);
  k_scan3<<<nb1, 256, 0, stream>>>(rs, boff, n, e);
  k_place<<<nbuk, 512, 0, stream>>>(bcnt, barr, rs, csr, n);

  k_wt_all<<<320, 256, 0, stream>>>(Wl0, Wr0, Wl1, Wr1, Wl2, Wr2, WTall);

  int gg = npad / 64;

  // layer 0
  k_gemm<256, false><<<gg, 256, 0, stream>>>(x, WTall, b0, bns, gm0, bt0, T16, Ha, n);
  k_agg128<<<NBAGG, 256, 0, stream>>>(rs, csr, T16, Ha, partials, n);
  k_red<<<256, 64, 0, stream>>>(partials, bns);
  // layer 1
  k_gemm<256, true><<<gg, 256, 0, stream>>>(Ha, WTall + 32768, b1, bns, gm0, bt0, T16, Hb, n);
  k_agg128<<<NBAGG, 256, 0, stream>>>(rs, csr, T16, Hb, partials, n);
  k_red<<<256, 64, 0, stream>>>(partials, bns);
  // layer 2
  k_gemm<128, true><<<gg, 256, 0, stream>>>(Hb, WTall + 65536, b2, bns, gm1, bt1, T16, Ha, n);
  k_agg64<<<NBAGG, 256, 0, stream>>>(rs, csr, T16, Ha, partials, n);
  k_red<<<128, 64, 0, stream>>>(partials, bns);
  int total4 = n * 64 / 4;
  int gn = (total4 + 255) / 256;
  if (gn > 2048) gn = 2048;
  k_bn_norm<64, false><<<gn, 256, 0, stream>>>(Ha, bns, gm2, bt2, (float*)d_out, n);
}